// Round 7
// baseline (262.676 us; speedup 1.0000x reference)
//
#include <hip/hip_runtime.h>

typedef unsigned short u16;
typedef unsigned int   u32;
typedef short bf16x8 __attribute__((ext_vector_type(8)));
typedef float f32x4  __attribute__((ext_vector_type(4)));
typedef float f32x2  __attribute__((ext_vector_type(2)));

#define BG    128      // graphs
#define NN    128      // nodes per graph
#define MS    16       // samples
#define KP    8        // pearl_k
#define HM    16       // mlp hidden
#define DP    64       // pe dims
#define NSUM  16384    // BG*NN
#define NE    262144   // edges
#define SITES 2048     // NN*MS

// R3: inputs f32, output f32. Intermediates bf16.
// R10: poly = MFMA split-precision.
// R11: agg2 m-sliced, persistent chunk ownership (53.6us agg2, 259 total).
// R12: +degree-sort +m/m+8 fusion: fusion = L2 thrash (FETCH 67->84MB). Sort good.
// R13: fusion reverted, batch-4, stride-balanced chunks: agg2 44.1us BUT total
//   260.3 vs R11's 259.2 -> ledger says k_perm (single-block, 32K serialized
//   LDS atomics on 64 bins) eats ~10us of serial GPU time. agg2 still
//   latency-bound: VALU 41%, HBM 32%, L2 ~35%, nothing saturated.
// R14 (this round):
//   (a) k_perm rewritten with per-wave sub-histograms hist[16][64] (16x less
//       atomic contention), wave-shfl scan, per-wave placement bases. ~1-2us.
//   (b) agg2 fast loop batch-8: lane q loads srcs[e0+i+q] (1 coalesced 32B
//       load/group/8-edges), __shfl broadcasts indices, 8 gathers in flight
//       (2x MLP, kills the per-edge srcs->gather serial chain).

__device__ __forceinline__ float blo(u32 u){ union{u32 i; float f;} v; v.i=u<<16; return v.f; }
__device__ __forceinline__ float bhi(u32 u){ union{u32 i; float f;} v; v.i=u&0xffff0000u; return v.f; }
__device__ __forceinline__ u16  f2b(float f){ union{float f; u32 i;} v; v.f=f; u32 x=v.i; x += 0x7fffu + ((x>>16)&1u); return (u16)(x>>16); }
__device__ __forceinline__ u32  pk2(float a, float b){ return (u32)f2b(a) | ((u32)f2b(b)<<16); }
__device__ __forceinline__ f32x2 up2(u32 u){ f32x2 v; v.x=blo(u); v.y=bhi(u); return v; }

__device__ __forceinline__ void fsplit(float x, short& hi, short& lo){
  u16 h = f2b(x); hi = (short)h; lo = (short)f2b(x - blo((u32)h));
}

__device__ __forceinline__ void acc4s(float* a, uint2 x, float s){
  a[0]+=s*blo(x.x); a[1]+=s*bhi(x.x); a[2]+=s*blo(x.y); a[3]+=s*bhi(x.y);
}

#define MFMA16(a,b,c) __builtin_amdgcn_mfma_f32_16x16x32_bf16(a,b,c,0,0,0)

__device__ __forceinline__ bf16x8 bfragW(const float* __restrict__ W, int nrows,
                                         int k0, int nb, int col, int quad){
  bf16x8 f;
  #pragma unroll
  for(int j=0;j<8;++j){
    int k = k0 + quad*8 + j;
    float v = (k < nrows) ? W[k*DP + nb + col] : 0.f;
    f[j] = (short)f2b(v);
  }
  return f;
}
__device__ __forceinline__ bf16x8 afragT(const float* tp){
  float4 v0 = *(const float4*)tp;
  float4 v1 = *(const float4*)(tp+4);
  bf16x8 a;
  a[0]=(short)f2b(v0.x); a[1]=(short)f2b(v0.y); a[2]=(short)f2b(v0.z); a[3]=(short)f2b(v0.w);
  a[4]=(short)f2b(v1.x); a[5]=(short)f2b(v1.y); a[6]=(short)f2b(v1.z); a[7]=(short)f2b(v1.w);
  return a;
}

// ---------------------------------------------------------------------------
// K1: poly filter via MFMA split-precision (R10, unchanged).
// ---------------------------------------------------------------------------
__global__ __launch_bounds__(256,1) void k_poly(
    const float* __restrict__ lap, const float* __restrict__ W0, const float* __restrict__ mlpW,
    const float* __restrict__ bng, const float* __restrict__ bnb, u16* __restrict__ h1,
    int* __restrict__ cnt)
{
  __shared__ float Wbuf[2][SITES];
  __shared__ float mlpWS[KP*HM];
  __shared__ float red[4][32];
  __shared__ float stat[32];
  __shared__ float ssc[HM], ssh[HM];

  const int b = blockIdx.x, t = threadIdx.x, l = t&63, w = t>>6;
  const int col = l&15, quad = l>>4;
  if (t < 128) cnt[b*128 + t] = 0;

  {
    const float4* src = (const float4*)(W0 + (size_t)b*SITES);
    for (int i=t; i<SITES/4; i+=256) ((float4*)Wbuf[0])[i] = src[i];
    if (t < KP*HM) mlpWS[t] = mlpW[t];
  }

  bf16x8 Ah[2][4], Al[2][4];
  {
    const float* lg = lap + (size_t)b*NN*NN;
    #pragma unroll
    for(int Mt=0;Mt<2;++Mt){
      const int nr = w*32 + Mt*16 + col;
      #pragma unroll
      for(int Kc=0;Kc<4;++Kc){
        const float* p = lg + (size_t)nr*NN + Kc*32 + quad*8;
        float4 v0 = *(const float4*)p;
        float4 v1 = *(const float4*)(p+4);
        float xs[8] = {v0.x,v0.y,v0.z,v0.w,v1.x,v1.y,v1.z,v1.w};
        #pragma unroll
        for(int j=0;j<8;++j){ short hi,lo; fsplit(xs[j],hi,lo); Ah[Mt][Kc][j]=hi; Al[Mt][Kc][j]=lo; }
      }
    }
  }

  float h[8][16];
  {
    const float* w0g = W0 + (size_t)b*SITES;
    #pragma unroll
    for(int Mt=0;Mt<2;++Mt){
      #pragma unroll
      for(int r=0;r<4;++r){
        const int n = w*32 + Mt*16 + quad*4 + r;
        float sv = w0g[n*MS + col];
        #pragma unroll
        for(int c=0;c<16;++c) h[Mt*4+r][c] = sv*mlpW[c];
      }
    }
  }
  __syncthreads();

  int cur=0;
  for(int k=1;k<KP;++k){
    f32x4 c0 = {0.f,0.f,0.f,0.f};
    f32x4 c1 = {0.f,0.f,0.f,0.f};
    #pragma unroll
    for(int Kc=0;Kc<4;++Kc){
      const float* wb = &Wbuf[cur][(Kc*32 + quad*8)*MS + col];
      bf16x8 Bh, Bl;
      #pragma unroll
      for(int j=0;j<8;++j){
        float x = wb[j*MS];
        short hi,lo; fsplit(x,hi,lo); Bh[j]=hi; Bl[j]=lo;
      }
      c0 = MFMA16(Ah[0][Kc], Bh, c0);
      c0 = MFMA16(Ah[0][Kc], Bl, c0);
      c0 = MFMA16(Al[0][Kc], Bh, c0);
      c1 = MFMA16(Ah[1][Kc], Bh, c1);
      c1 = MFMA16(Ah[1][Kc], Bl, c1);
      c1 = MFMA16(Al[1][Kc], Bh, c1);
    }
    float mw[16];
    #pragma unroll
    for(int c=0;c<16;++c) mw[c]=mlpWS[k*16+c];
    #pragma unroll
    for(int r=0;r<4;++r){
      const int n0 = w*32 + quad*4 + r;
      Wbuf[cur^1][n0*MS + col]        = c0[r];
      Wbuf[cur^1][(n0+16)*MS + col]   = c1[r];
      #pragma unroll
      for(int c=0;c<16;++c){ h[r][c] += c0[r]*mw[c]; h[4+r][c] += c1[r]*mw[c]; }
    }
    __syncthreads();
    cur ^= 1;
  }

  float sum[16], sq[16];
  #pragma unroll
  for(int c=0;c<16;++c){ sum[c]=0.f; sq[c]=0.f; }
  #pragma unroll
  for(int s=0;s<8;++s){
    #pragma unroll
    for(int c=0;c<16;++c){ float v=h[s][c]; sum[c]+=v; sq[c]+=v*v; }
  }
  #pragma unroll
  for(int d=1;d<64;d<<=1){
    #pragma unroll
    for(int c=0;c<16;++c){ sum[c]+=__shfl_xor(sum[c],d,64); sq[c]+=__shfl_xor(sq[c],d,64); }
  }
  if(l==0){
    #pragma unroll
    for(int c=0;c<16;++c){ red[w][c]=sum[c]; red[w][16+c]=sq[c]; }
  }
  __syncthreads();
  if(t<32) stat[t]=red[0][t]+red[1][t]+red[2][t]+red[3][t];
  __syncthreads();
  if(t<16){
    float mu  = stat[t]*(1.f/SITES);
    float var = stat[16+t]*(1.f/SITES) - mu*mu;
    float sc  = bng[t] * rsqrtf(var + 1e-5f);
    ssc[t]=sc; ssh[t]=bnb[t] - mu*sc;
  }
  __syncthreads();
  {
    float sc[16], sh[16];
    #pragma unroll
    for(int c=0;c<16;++c){ sc[c]=ssc[c]; sh[c]=ssh[c]; }
    #pragma unroll
    for(int s=0;s<8;++s){
      const int n = w*32 + (s>>2)*16 + quad*4 + (s&3);
      const int node = b*NN + n;
      float r[16];
      #pragma unroll
      for(int c=0;c<16;++c) r[c]=fmaxf(h[s][c]*sc[c]+sh[c], 0.f);
      uint4 A;
      A.x=pk2(r[0],r[1]);  A.y=pk2(r[2],r[3]);  A.z=pk2(r[4],r[5]);  A.w=pk2(r[6],r[7]);
      uint4 Bv;
      Bv.x=pk2(r[8],r[9]); Bv.y=pk2(r[10],r[11]); Bv.z=pk2(r[12],r[13]); Bv.w=pk2(r[14],r[15]);
      u16* o = h1 + (size_t)node*256 + (size_t)col*HM;
      *(uint4*)o     = A;
      *(uint4*)(o+8) = Bv;
    }
  }
}

// --------------------------- CSR build (by dst) ----------------------------
__global__ void k_hist(const int* __restrict__ dst, int* __restrict__ cnt){
  int e = blockIdx.x*256 + threadIdx.x;
  atomicAdd(&cnt[dst[e]], 1);
}

__global__ void k_scan(const int* __restrict__ cnt, int* __restrict__ off, int* __restrict__ wpos){
  __shared__ int ps[256];
  const int t = threadIdx.x, PER = NSUM/256;
  int s=0;
  for(int i=0;i<PER;++i) s += cnt[t*PER+i];
  ps[t]=s; __syncthreads();
  for(int d=1; d<256; d<<=1){
    int v = (t>=d) ? ps[t-d] : 0;
    __syncthreads();
    ps[t] += v;
    __syncthreads();
  }
  int run = (t==0) ? 0 : ps[t-1];
  for(int i=0;i<PER;++i){
    int idx=t*PER+i;
    off[idx]=run; wpos[idx]=run;
    run += cnt[idx];
  }
  if(t==255) off[NSUM]=run;
}

__global__ void k_scatter(const int* __restrict__ srcI, const int* __restrict__ dstI,
                          int* __restrict__ wpos, int* __restrict__ srcs){
  int e = blockIdx.x*256 + threadIdx.x;
  int p = atomicAdd(&wpos[dstI[e]], 1);
  srcs[p] = srcI[e];
}

// ---------------------------------------------------------------------------
// K-perm R14: degree-sorted node permutation, low-contention counting sort.
// Per-wave sub-histograms hist[16][64] (atomics contend only inside a wave),
// wave-0 shfl-scan of the 64 bins, wave-1 builds per-wave placement bases,
// then per-wave-atomic placement. Single block, 1024 threads, ~16x less
// serialized atomic pressure than the R12/R13 version (~10us -> ~1-2us).
// ---------------------------------------------------------------------------
__global__ __launch_bounds__(1024) void k_perm(const int* __restrict__ cnt,
                                               int* __restrict__ perm){
  __shared__ int hist[16][64];
  __shared__ int base[64];
  __shared__ int wbase[16][64];
  const int t = threadIdx.x, w = t>>6, l = t&63;
  hist[w][l] = 0;                       // 16x64 = 1024 = blockDim
  __syncthreads();

  int mybin[16];
  #pragma unroll
  for (int i=0;i<16;++i){
    int n = i*1024 + t;                 // coalesced over cnt
    int b = min(cnt[n], 63);
    mybin[i] = b;
    atomicAdd(&hist[w][b], 1);          // within-wave contention only
  }
  __syncthreads();

  if (w == 0){                          // lane l = bin l
    int s = 0;
    #pragma unroll
    for (int k=0;k<16;++k) s += hist[k][l];
    int v = s;                          // inclusive shfl scan over 64 bins
    #pragma unroll
    for (int d=1; d<64; d<<=1){
      int u = __shfl_up(v, d, 64);
      if (l >= d) v += u;
    }
    base[l] = v - s;                    // exclusive
  }
  __syncthreads();

  if (w == 1){                          // per-wave bases for bin l
    int run = base[l];
    #pragma unroll
    for (int k=0;k<16;++k){ wbase[k][l] = run; run += hist[k][l]; }
  }
  __syncthreads();

  #pragma unroll
  for (int i=0;i<16;++i){
    int p = atomicAdd(&wbase[w][mybin[i]], 1);
    perm[p] = i*1024 + t;
  }
}

// ---------------------------------------------------------------------------
// K4a: GIN-1 aggregate (R5/R10). 1 node/wave, persistent lane ownership,
// batch-8. h1/z1 row-major. (unchanged)
// ---------------------------------------------------------------------------
__global__ __launch_bounds__(256) void k_agg1(
  const u16* __restrict__ h1, const float* __restrict__ eps1p,
  const int* __restrict__ off, const int* __restrict__ srcs, u16* __restrict__ z1)
{
  const int t=threadIdx.x, l=t&63;
  const int node = blockIdx.x*4 + (t>>6);
  const float epe = 1.f + eps1p[0];
  float a[4] = {0.f,0.f,0.f,0.f};
  acc4s(a, *(const uint2*)&h1[(size_t)node*256 + l*4], epe);
  int e=off[node]; const int e1=off[node+1];
  for(; e+8<=e1; e+=8){
    int s0=srcs[e],s1=srcs[e+1],s2=srcs[e+2],s3=srcs[e+3];
    int s4=srcs[e+4],s5=srcs[e+5],s6=srcs[e+6],s7=srcs[e+7];
    uint2 r0=*(const uint2*)&h1[(size_t)s0*256 + l*4];
    uint2 r1=*(const uint2*)&h1[(size_t)s1*256 + l*4];
    uint2 r2=*(const uint2*)&h1[(size_t)s2*256 + l*4];
    uint2 r3=*(const uint2*)&h1[(size_t)s3*256 + l*4];
    uint2 r4=*(const uint2*)&h1[(size_t)s4*256 + l*4];
    uint2 r5=*(const uint2*)&h1[(size_t)s5*256 + l*4];
    uint2 r6=*(const uint2*)&h1[(size_t)s6*256 + l*4];
    uint2 r7=*(const uint2*)&h1[(size_t)s7*256 + l*4];
    acc4s(a,r0,1.f); acc4s(a,r1,1.f); acc4s(a,r2,1.f); acc4s(a,r3,1.f);
    acc4s(a,r4,1.f); acc4s(a,r5,1.f); acc4s(a,r6,1.f); acc4s(a,r7,1.f);
  }
  for(; e<e1; ++e){
    uint2 r=*(const uint2*)&h1[(size_t)srcs[e]*256 + l*4];
    acc4s(a,r,1.f);
  }
  uint2 o; o.x=pk2(a[0],a[1]); o.y=pk2(a[2],a[3]);
  *(uint2*)&z1[(size_t)node*256 + l*4] = o;
}

// ---------------------------------------------------------------------------
// K5a: GIN-2 aggregate, R14.
// One m-slice per block (slice m pinned to XCD m&7, ~2MB L2-resident).
// 4 waves x 8 nodes; lane: grp=l>>3 (node), q=l&7 (16B chunk). Degree-sorted
// stride-balanced chunks (wave w of block g takes sorted chunk w*512+g).
// Fast loop batch-8: lane q loads srcs[e0+i+q] (ONE coalesced 32B load per
// group per 8 edges), __shfl broadcasts the 8 indices, 8 gathers in flight.
// Then unpredicated batch-4, then predicated batch-1 tail (sort makes the
// tail 0-2 iters). z2 row-major [node][m][d].
// ---------------------------------------------------------------------------
__global__ __launch_bounds__(256) void k_agg2(
  const u16* __restrict__ h2T, const float* __restrict__ eps2p,
  const int* __restrict__ off, const int* __restrict__ srcs,
  const int* __restrict__ perm, u16* __restrict__ z2)
{
  const int t=threadIdx.x, l=t&63, w=t>>6;
  const int m = blockIdx.x & 15, g = blockIdx.x >> 4;   // g in [0,512)
  const int grp = l>>3, q = l&7;
  const int chunk = w*512 + g;                          // [0,2048)
  const int node = perm[chunk*8 + grp];
  const float epe = 1.f + eps2p[0];
  const u16* __restrict__ base = h2T + (size_t)m*(NSUM*DP);

  f32x2 A[4];
  {
    uint4 x = *(const uint4*)&base[(size_t)node*DP + q*8];
    f32x2 s2; s2.x=epe; s2.y=epe;
    A[0]=s2*up2(x.x); A[1]=s2*up2(x.y); A[2]=s2*up2(x.z); A[3]=s2*up2(x.w);
  }
  const int e0 = off[node], e1 = off[node+1];
  int dmin = e1 - e0, dmax = dmin;
  #pragma unroll
  for(int d=1; d<64; d<<=1){
    dmin = min(dmin, __shfl_xor(dmin, d, 64));
    dmax = max(dmax, __shfl_xor(dmax, d, 64));
  }

  int i = 0;
  // batch-8 fast path: 1 coalesced srcs load + 8 shfl + 8 gathers in flight.
  for(; i+8 <= dmin; i += 8){
    int myidx = srcs[e0 + i + q];
    #pragma unroll
    for(int e=0; e<8; ++e){
      int idx = __shfl(myidx, grp*8 + e, 64);
      uint4 x = *(const uint4*)&base[(size_t)idx*DP + q*8];
      A[0]+=up2(x.x); A[1]+=up2(x.y); A[2]+=up2(x.z); A[3]+=up2(x.w);
    }
  }
  // batch-4 unpredicated mid-block.
  if (i+4 <= dmin){
    int i0 = srcs[e0+i],   i1 = srcs[e0+i+1];
    int i2 = srcs[e0+i+2], i3 = srcs[e0+i+3];
    uint4 x0 = *(const uint4*)&base[(size_t)i0*DP + q*8];
    uint4 x1 = *(const uint4*)&base[(size_t)i1*DP + q*8];
    uint4 x2 = *(const uint4*)&base[(size_t)i2*DP + q*8];
    uint4 x3 = *(const uint4*)&base[(size_t)i3*DP + q*8];
    A[0]+=up2(x0.x); A[1]+=up2(x0.y); A[2]+=up2(x0.z); A[3]+=up2(x0.w);
    A[0]+=up2(x1.x); A[1]+=up2(x1.y); A[2]+=up2(x1.z); A[3]+=up2(x1.w);
    A[0]+=up2(x2.x); A[1]+=up2(x2.y); A[2]+=up2(x2.z); A[3]+=up2(x2.w);
    A[0]+=up2(x3.x); A[1]+=up2(x3.y); A[2]+=up2(x3.z); A[3]+=up2(x3.w);
    i += 4;
  }
  // predicated batch-1 tail (sorted -> short).
  for(; i < dmax; ++i){
    int pa = e0+i;
    float sa = (pa < e1) ? 1.f : 0.f;
    int ea = min(pa, NE-1);
    int ia = srcs[ea];
    uint4 xa = *(const uint4*)&base[(size_t)ia*DP + q*8];
    f32x2 va; va.x=sa; va.y=sa;
    A[0]+=va*up2(xa.x); A[1]+=va*up2(xa.y); A[2]+=va*up2(xa.z); A[3]+=va*up2(xa.w);
  }

  uint4 o;
  o.x=pk2(A[0].x,A[0].y); o.y=pk2(A[1].x,A[1].y);
  o.z=pk2(A[2].x,A[2].y); o.w=pk2(A[3].x,A[3].y);
  *(uint4*)&z2[(size_t)node*1024 + m*DP + q*8] = o;
}

// ---------------------------------------------------------------------------
// K4b: GIN-1 MLP via MFMA; writes h2 TRANSPOSED h2T[m][node][d]. (unchanged)
// ---------------------------------------------------------------------------
__global__ __launch_bounds__(256) void k_mm1(
  const u16* __restrict__ z1, const float* __restrict__ W1a, const float* __restrict__ b1a,
  const float* __restrict__ W1b, const float* __restrict__ b1b, u16* __restrict__ h2T)
{
  __shared__ float tS[4][16*68 + 4];
  const int t=threadIdx.x, l=t&63, w=t>>6;
  const int col=l&15, quad=l>>4;

  bf16x8 fa[4], fb[4][2];
  float bav[4], bbv[4];
  #pragma unroll
  for(int nt=0;nt<4;++nt){
    fa[nt]    = bfragW(W1a, HM, 0,  nt*16, col, quad);   // k>=16 zeroed
    fb[nt][0] = bfragW(W1b, DP, 0,  nt*16, col, quad);
    fb[nt][1] = bfragW(W1b, DP, 32, nt*16, col, quad);
    bav[nt] = b1a[nt*16+col];
    bbv[nt] = b1b[nt*16+col];
  }
  for(int ni=0;ni<2;++ni){
    const int node = blockIdx.x*8 + ni*4 + w;
    bf16x8 a0;
    #pragma unroll
    for(int j=0;j<8;++j) a0[j]=0;
    if (quad < 2) a0 = *(const bf16x8*)&z1[(size_t)node*256 + col*16 + quad*8];
    #pragma unroll
    for(int nt=0;nt<4;++nt){
      f32x4 c = {bav[nt], bav[nt], bav[nt], bav[nt]};
      c = MFMA16(a0, fa[nt], c);
      #pragma unroll
      for(int r=0;r<4;++r)
        tS[w][(quad*4+r)*68 + nt*16 + col] = fmaxf(c[r], 0.f);
    }
    bf16x8 ta0 = afragT(&tS[w][col*68 + quad*8]);
    bf16x8 ta1 = afragT(&tS[w][col*68 + 32 + quad*8]);
    #pragma unroll
    for(int nt=0;nt<4;++nt){
      f32x4 c = {bbv[nt], bbv[nt], bbv[nt], bbv[nt]};
      c = MFMA16(ta0, fb[nt][0], c);
      c = MFMA16(ta1, fb[nt][1], c);
      #pragma unroll
      for(int r=0;r<4;++r)
        h2T[((size_t)(quad*4+r)*NSUM + node)*DP + nt*16 + col] = f2b(fmaxf(c[r], 0.f));
    }
  }
}

// ---------------------------------------------------------------------------
// K5b: GIN-2 MLP via MFMA + ReLU + sum over M -> out f32 [NSUM,64]. (unchanged)
// ---------------------------------------------------------------------------
__global__ __launch_bounds__(256) void k_mm2(
  const u16* __restrict__ z2, const float* __restrict__ W2a, const float* __restrict__ b2a,
  const float* __restrict__ W2b, const float* __restrict__ b2b, float* __restrict__ out)
{
  __shared__ float tS[4][16*68 + 4];
  const int t=threadIdx.x, l=t&63, w=t>>6;
  const int col=l&15, quad=l>>4;

  bf16x8 fa[4][2], fb[4][2];
  float bav[4], bbv[4];
  #pragma unroll
  for(int nt=0;nt<4;++nt){
    fa[nt][0] = bfragW(W2a, DP, 0,  nt*16, col, quad);
    fa[nt][1] = bfragW(W2a, DP, 32, nt*16, col, quad);
    fb[nt][0] = bfragW(W2b, DP, 0,  nt*16, col, quad);
    fb[nt][1] = bfragW(W2b, DP, 32, nt*16, col, quad);
    bav[nt] = b2a[nt*16+col];
    bbv[nt] = b2b[nt*16+col];
  }
  for(int ni=0;ni<2;++ni){
    const int node = blockIdx.x*8 + ni*4 + w;
    const u16* zrow = &z2[(size_t)node*1024];
    bf16x8 a0 = *(const bf16x8*)&zrow[col*64 + quad*8];
    bf16x8 a1 = *(const bf16x8*)&zrow[col*64 + quad*8 + 32];
    #pragma unroll
    for(int nt=0;nt<4;++nt){
      f32x4 c = {bav[nt], bav[nt], bav[nt], bav[nt]};
      c = MFMA16(a0, fa[nt][0], c);
      c = MFMA16(a1, fa[nt][1], c);
      #pragma unroll
      for(int r=0;r<4;++r)
        tS[w][(quad*4+r)*68 + nt*16 + col] = fmaxf(c[r], 0.f);
    }
    bf16x8 ta0 = afragT(&tS[w][col*68 + quad*8]);
    bf16x8 ta1 = afragT(&tS[w][col*68 + 32 + quad*8]);
    #pragma unroll
    for(int nt=0;nt<4;++nt){
      f32x4 c = {bbv[nt], bbv[nt], bbv[nt], bbv[nt]};
      c = MFMA16(ta0, fb[nt][0], c);
      c = MFMA16(ta1, fb[nt][1], c);
      float s = fmaxf(c[0],0.f)+fmaxf(c[1],0.f)+fmaxf(c[2],0.f)+fmaxf(c[3],0.f);
      s += __shfl_xor(s, 16, 64);
      s += __shfl_xor(s, 32, 64);
      if (quad == 0)
        out[(size_t)node*64 + nt*16 + col] = s;
    }
  }
}

extern "C" void kernel_launch(void* const* d_in, const int* in_sizes, int n_in,
                              void* d_out, int out_size, void* d_ws, size_t ws_size,
                              hipStream_t stream)
{
  (void)in_sizes; (void)n_in; (void)out_size; (void)ws_size;
  const float* lap  = (const float*)d_in[0];
  const float* W0   = (const float*)d_in[1];
  const float* mlpW = (const float*)d_in[2];
  // d_in[3] = mlp_b: cancels inside BatchNorm (pure mean shift)
  const float* bng  = (const float*)d_in[4];
  const float* bnb  = (const float*)d_in[5];
  const float* eps1 = (const float*)d_in[6];
  const float* W1a  = (const float*)d_in[7];
  const float* b1a  = (const float*)d_in[8];
  const float* W1b  = (const float*)d_in[9];
  const float* b1b  = (const float*)d_in[10];
  const float* eps2 = (const float*)d_in[11];
  const float* W2a  = (const float*)d_in[12];
  const float* b2a  = (const float*)d_in[13];
  const float* W2b  = (const float*)d_in[14];
  const float* b2b  = (const float*)d_in[15];
  const int*   ei   = (const int*)d_in[16];
  const int* srcI = ei;
  const int* dstI = ei + NE;

  char* ws = (char*)d_ws;
  u16* h1   = (u16*)(ws);                    //  8,388,608 B  [16384][16][16]
  u16* z1   = (u16*)(ws + 8388608);          //  8,388,608 B
  u16* h2T  = (u16*)(ws + 16777216);         // 33,554,432 B  [16][16384][64]
  u16* z2   = (u16*)(ws + 50331648);         // 33,554,432 B  [16384][16][64]
  int* cnt  = (int*)(ws + 83886080);         //     65,536 B
  int* offA = (int*)(ws + 83951616);         //     65,792 B
  int* wpos = (int*)(ws + 84017408);         //     65,536 B (reused as perm)
  int* srcs = (int*)(ws + 84082944);         //  1,048,576 B  (end 85,131,520)
  int* perm = wpos;  // wpos fully consumed by k_scatter before k_perm runs

  k_poly   <<<BG,      256, 0, stream>>>(lap, W0, mlpW, bng, bnb, h1, cnt);
  k_hist   <<<NE/256,  256, 0, stream>>>(dstI, cnt);
  k_scan   <<<1,       256, 0, stream>>>(cnt, offA, wpos);
  k_scatter<<<NE/256,  256, 0, stream>>>(srcI, dstI, wpos, srcs);
  k_perm   <<<1,      1024, 0, stream>>>(cnt, perm);
  k_agg1   <<<NSUM/4,  256, 0, stream>>>(h1, eps1, offA, srcs, z1);
  k_mm1    <<<NSUM/8,  256, 0, stream>>>(z1, W1a, b1a, W1b, b1b, h2T);
  k_agg2   <<<16*(NSUM/32), 256, 0, stream>>>(h2T, eps2, offA, srcs, perm, z2);
  k_mm2    <<<NSUM/8,  256, 0, stream>>>(z2, W2a, b2a, W2b, b2b, (float*)d_out);
}

// Round 9
// 248.427 us; speedup vs baseline: 1.0574x; 1.0574x over previous
//
#include <hip/hip_runtime.h>

typedef unsigned short u16;
typedef unsigned int   u32;
typedef short bf16x8 __attribute__((ext_vector_type(8)));
typedef float f32x4  __attribute__((ext_vector_type(4)));
typedef float f32x2  __attribute__((ext_vector_type(2)));

#define BG    128      // graphs
#define NN    128      // nodes per graph
#define MS    16       // samples
#define KP    8        // pearl_k
#define HM    16       // mlp hidden
#define DP    64       // pe dims
#define NSUM  16384    // BG*NN
#define NE    262144   // edges
#define SITES 2048     // NN*MS

// R11: agg2 m-sliced, persistent chunk ownership (53.6us agg2, 259 total).
// R12: degree-sort good; m/m+8 fusion = L2 thrash (FETCH 67->84MB).
// R13: fusion reverted, batch-4: agg2 44.1us. FETCH 77MB (srcs read
//   amplification from sorted-scattered edge lists); single-block perm+scan
//   eat the win in serial time.
// R14: batch-8 shfl REGRESSED agg2 (VGPR 28->48, occ 53->36%). Reverted.
// R15 (resubmit — R8 bench was a GPU-acquisition timeout, kernel untested):
//   perm-ordered edge array, computed for free.
//   After counting sort, every node in degree-bin b has degree exactly b, so
//   edge offsets in sorted order are ebase[b] + j*b — k_perm computes perm,
//   offP (contiguous sorted-order edge offsets) AND wpos (scatter cursors)
//   with one extra shfl-scan. k_scan DELETED. k_scatter writes srcs directly
//   in perm order -> agg1/agg2 edge reads stream contiguously (kills the
//   +10MB FETCH). agg2 loop = R13 batch-4 (28 VGPR). agg1 also sorted-
//   position-indexed (balanced + streaming).
//   Buffers (no growth): cnt-slot = cnt then wpos (in-place safe),
//   offA-slot = offP, wpos-slot = perm.

__device__ __forceinline__ float blo(u32 u){ union{u32 i; float f;} v; v.i=u<<16; return v.f; }
__device__ __forceinline__ float bhi(u32 u){ union{u32 i; float f;} v; v.i=u&0xffff0000u; return v.f; }
__device__ __forceinline__ u16  f2b(float f){ union{float f; u32 i;} v; v.f=f; u32 x=v.i; x += 0x7fffu + ((x>>16)&1u); return (u16)(x>>16); }
__device__ __forceinline__ u32  pk2(float a, float b){ return (u32)f2b(a) | ((u32)f2b(b)<<16); }
__device__ __forceinline__ f32x2 up2(u32 u){ f32x2 v; v.x=blo(u); v.y=bhi(u); return v; }

__device__ __forceinline__ void fsplit(float x, short& hi, short& lo){
  u16 h = f2b(x); hi = (short)h; lo = (short)f2b(x - blo((u32)h));
}

__device__ __forceinline__ void acc4s(float* a, uint2 x, float s){
  a[0]+=s*blo(x.x); a[1]+=s*bhi(x.x); a[2]+=s*blo(x.y); a[3]+=s*bhi(x.y);
}

#define MFMA16(a,b,c) __builtin_amdgcn_mfma_f32_16x16x32_bf16(a,b,c,0,0,0)

__device__ __forceinline__ bf16x8 bfragW(const float* __restrict__ W, int nrows,
                                         int k0, int nb, int col, int quad){
  bf16x8 f;
  #pragma unroll
  for(int j=0;j<8;++j){
    int k = k0 + quad*8 + j;
    float v = (k < nrows) ? W[k*DP + nb + col] : 0.f;
    f[j] = (short)f2b(v);
  }
  return f;
}
__device__ __forceinline__ bf16x8 afragT(const float* tp){
  float4 v0 = *(const float4*)tp;
  float4 v1 = *(const float4*)(tp+4);
  bf16x8 a;
  a[0]=(short)f2b(v0.x); a[1]=(short)f2b(v0.y); a[2]=(short)f2b(v0.z); a[3]=(short)f2b(v0.w);
  a[4]=(short)f2b(v1.x); a[5]=(short)f2b(v1.y); a[6]=(short)f2b(v1.z); a[7]=(short)f2b(v1.w);
  return a;
}

// ---------------------------------------------------------------------------
// K1: poly filter via MFMA split-precision (R10, unchanged).
// ---------------------------------------------------------------------------
__global__ __launch_bounds__(256,1) void k_poly(
    const float* __restrict__ lap, const float* __restrict__ W0, const float* __restrict__ mlpW,
    const float* __restrict__ bng, const float* __restrict__ bnb, u16* __restrict__ h1,
    int* __restrict__ cnt)
{
  __shared__ float Wbuf[2][SITES];
  __shared__ float mlpWS[KP*HM];
  __shared__ float red[4][32];
  __shared__ float stat[32];
  __shared__ float ssc[HM], ssh[HM];

  const int b = blockIdx.x, t = threadIdx.x, l = t&63, w = t>>6;
  const int col = l&15, quad = l>>4;
  if (t < 128) cnt[b*128 + t] = 0;

  {
    const float4* src = (const float4*)(W0 + (size_t)b*SITES);
    for (int i=t; i<SITES/4; i+=256) ((float4*)Wbuf[0])[i] = src[i];
    if (t < KP*HM) mlpWS[t] = mlpW[t];
  }

  bf16x8 Ah[2][4], Al[2][4];
  {
    const float* lg = lap + (size_t)b*NN*NN;
    #pragma unroll
    for(int Mt=0;Mt<2;++Mt){
      const int nr = w*32 + Mt*16 + col;
      #pragma unroll
      for(int Kc=0;Kc<4;++Kc){
        const float* p = lg + (size_t)nr*NN + Kc*32 + quad*8;
        float4 v0 = *(const float4*)p;
        float4 v1 = *(const float4*)(p+4);
        float xs[8] = {v0.x,v0.y,v0.z,v0.w,v1.x,v1.y,v1.z,v1.w};
        #pragma unroll
        for(int j=0;j<8;++j){ short hi,lo; fsplit(xs[j],hi,lo); Ah[Mt][Kc][j]=hi; Al[Mt][Kc][j]=lo; }
      }
    }
  }

  float h[8][16];
  {
    const float* w0g = W0 + (size_t)b*SITES;
    #pragma unroll
    for(int Mt=0;Mt<2;++Mt){
      #pragma unroll
      for(int r=0;r<4;++r){
        const int n = w*32 + Mt*16 + quad*4 + r;
        float sv = w0g[n*MS + col];
        #pragma unroll
        for(int c=0;c<16;++c) h[Mt*4+r][c] = sv*mlpW[c];
      }
    }
  }
  __syncthreads();

  int cur=0;
  for(int k=1;k<KP;++k){
    f32x4 c0 = {0.f,0.f,0.f,0.f};
    f32x4 c1 = {0.f,0.f,0.f,0.f};
    #pragma unroll
    for(int Kc=0;Kc<4;++Kc){
      const float* wb = &Wbuf[cur][(Kc*32 + quad*8)*MS + col];
      bf16x8 Bh, Bl;
      #pragma unroll
      for(int j=0;j<8;++j){
        float x = wb[j*MS];
        short hi,lo; fsplit(x,hi,lo); Bh[j]=hi; Bl[j]=lo;
      }
      c0 = MFMA16(Ah[0][Kc], Bh, c0);
      c0 = MFMA16(Ah[0][Kc], Bl, c0);
      c0 = MFMA16(Al[0][Kc], Bh, c0);
      c1 = MFMA16(Ah[1][Kc], Bh, c1);
      c1 = MFMA16(Ah[1][Kc], Bl, c1);
      c1 = MFMA16(Al[1][Kc], Bh, c1);
    }
    float mw[16];
    #pragma unroll
    for(int c=0;c<16;++c) mw[c]=mlpWS[k*16+c];
    #pragma unroll
    for(int r=0;r<4;++r){
      const int n0 = w*32 + quad*4 + r;
      Wbuf[cur^1][n0*MS + col]        = c0[r];
      Wbuf[cur^1][(n0+16)*MS + col]   = c1[r];
      #pragma unroll
      for(int c=0;c<16;++c){ h[r][c] += c0[r]*mw[c]; h[4+r][c] += c1[r]*mw[c]; }
    }
    __syncthreads();
    cur ^= 1;
  }

  float sum[16], sq[16];
  #pragma unroll
  for(int c=0;c<16;++c){ sum[c]=0.f; sq[c]=0.f; }
  #pragma unroll
  for(int s=0;s<8;++s){
    #pragma unroll
    for(int c=0;c<16;++c){ float v=h[s][c]; sum[c]+=v; sq[c]+=v*v; }
  }
  #pragma unroll
  for(int d=1;d<64;d<<=1){
    #pragma unroll
    for(int c=0;c<16;++c){ sum[c]+=__shfl_xor(sum[c],d,64); sq[c]+=__shfl_xor(sq[c],d,64); }
  }
  if(l==0){
    #pragma unroll
    for(int c=0;c<16;++c){ red[w][c]=sum[c]; red[w][16+c]=sq[c]; }
  }
  __syncthreads();
  if(t<32) stat[t]=red[0][t]+red[1][t]+red[2][t]+red[3][t];
  __syncthreads();
  if(t<16){
    float mu  = stat[t]*(1.f/SITES);
    float var = stat[16+t]*(1.f/SITES) - mu*mu;
    float sc  = bng[t] * rsqrtf(var + 1e-5f);
    ssc[t]=sc; ssh[t]=bnb[t] - mu*sc;
  }
  __syncthreads();
  {
    float sc[16], sh[16];
    #pragma unroll
    for(int c=0;c<16;++c){ sc[c]=ssc[c]; sh[c]=ssh[c]; }
    #pragma unroll
    for(int s=0;s<8;++s){
      const int n = w*32 + (s>>2)*16 + quad*4 + (s&3);
      const int node = b*NN + n;
      float r[16];
      #pragma unroll
      for(int c=0;c<16;++c) r[c]=fmaxf(h[s][c]*sc[c]+sh[c], 0.f);
      uint4 A;
      A.x=pk2(r[0],r[1]);  A.y=pk2(r[2],r[3]);  A.z=pk2(r[4],r[5]);  A.w=pk2(r[6],r[7]);
      uint4 Bv;
      Bv.x=pk2(r[8],r[9]); Bv.y=pk2(r[10],r[11]); Bv.z=pk2(r[12],r[13]); Bv.w=pk2(r[14],r[15]);
      u16* o = h1 + (size_t)node*256 + (size_t)col*HM;
      *(uint4*)o     = A;
      *(uint4*)(o+8) = Bv;
    }
  }
}

// --------------------------- CSR build (by dst) ----------------------------
__global__ void k_hist(const int* __restrict__ dst, int* __restrict__ cnt){
  int e = blockIdx.x*256 + threadIdx.x;
  atomicAdd(&cnt[dst[e]], 1);
}

// ---------------------------------------------------------------------------
// K-perm R15: counting sort by degree (64 bins) that ALSO emits perm-ordered
// edge offsets for free. All nodes in bin b have degree exactly b, so the
// j-th node of bin b starts at ebase[b] + j*b (ebase = scan of count[b]*b).
// Outputs: perm[pos]=node, offP[pos]=edge start (contiguous in sorted order),
// cntw[node]=same value (scatter cursor; overwrites cnt in place — all cnt
// reads are cached in mybin[] before the first write, separated by barriers).
// Per-wave sub-histograms keep LDS atomic contention within a wave.
// Replaces BOTH the old k_perm and k_scan.
// ---------------------------------------------------------------------------
__global__ __launch_bounds__(1024) void k_perm(int* cntw, int* __restrict__ perm,
                                               int* __restrict__ offP){
  __shared__ int hist[16][64];
  __shared__ int base[64];
  __shared__ int ebase[64];
  __shared__ int wbase[16][64];
  const int t = threadIdx.x, w = t>>6, l = t&63;
  hist[w][l] = 0;                       // 16x64 = 1024 = blockDim
  __syncthreads();

  int mybin[16];
  #pragma unroll
  for (int i=0;i<16;++i){
    int n = i*1024 + t;                 // coalesced over cnt
    int b = min(cntw[n], 63);
    mybin[i] = b;
    atomicAdd(&hist[w][b], 1);          // within-wave contention only
  }
  __syncthreads();

  if (w == 0){                          // lane l = bin l: dual shfl scan
    int s = 0;
    #pragma unroll
    for (int k=0;k<16;++k) s += hist[k][l];
    int se = s * l;                     // edges in bin l
    int v = s, ve = se;
    #pragma unroll
    for (int d=1; d<64; d<<=1){
      int u  = __shfl_up(v,  d, 64);
      int ue = __shfl_up(ve, d, 64);
      if (l >= d){ v += u; ve += ue; }
    }
    base[l]  = v  - s;                  // exclusive node-space
    ebase[l] = ve - se;                 // exclusive edge-space
  }
  __syncthreads();

  if (w == 1){                          // per-wave placement bases for bin l
    int run = base[l];
    #pragma unroll
    for (int k=0;k<16;++k){ wbase[k][l] = run; run += hist[k][l]; }
  }
  __syncthreads();

  #pragma unroll
  for (int i=0;i<16;++i){
    int b    = mybin[i];
    int pos  = atomicAdd(&wbase[w][b], 1);
    int node = i*1024 + t;
    int e0   = ebase[b] + (pos - base[b]) * b;
    perm[pos] = node;
    offP[pos] = e0;
    cntw[node] = e0;                    // scatter cursor (wpos)
  }
  if (t == 0) offP[NSUM] = NE;
}

__global__ void k_scatter(const int* __restrict__ srcI, const int* __restrict__ dstI,
                          int* __restrict__ wpos, int* __restrict__ srcs){
  int e = blockIdx.x*256 + threadIdx.x;
  int p = atomicAdd(&wpos[dstI[e]], 1);
  srcs[p] = srcI[e];
}

// ---------------------------------------------------------------------------
// K4a: GIN-1 aggregate, sorted-position-indexed. 1 node/wave, persistent lane
// ownership, batch-8. Edge lists stream contiguously from perm-ordered srcs.
// ---------------------------------------------------------------------------
__global__ __launch_bounds__(256) void k_agg1(
  const u16* __restrict__ h1, const float* __restrict__ eps1p,
  const int* __restrict__ offP, const int* __restrict__ perm,
  const int* __restrict__ srcs, u16* __restrict__ z1)
{
  const int t=threadIdx.x, l=t&63;
  const int p = blockIdx.x*4 + (t>>6);
  const int node = perm[p];
  const float epe = 1.f + eps1p[0];
  float a[4] = {0.f,0.f,0.f,0.f};
  acc4s(a, *(const uint2*)&h1[(size_t)node*256 + l*4], epe);
  int e = offP[p]; const int e1 = offP[p+1];
  for(; e+8<=e1; e+=8){
    int s0=srcs[e],s1=srcs[e+1],s2=srcs[e+2],s3=srcs[e+3];
    int s4=srcs[e+4],s5=srcs[e+5],s6=srcs[e+6],s7=srcs[e+7];
    uint2 r0=*(const uint2*)&h1[(size_t)s0*256 + l*4];
    uint2 r1=*(const uint2*)&h1[(size_t)s1*256 + l*4];
    uint2 r2=*(const uint2*)&h1[(size_t)s2*256 + l*4];
    uint2 r3=*(const uint2*)&h1[(size_t)s3*256 + l*4];
    uint2 r4=*(const uint2*)&h1[(size_t)s4*256 + l*4];
    uint2 r5=*(const uint2*)&h1[(size_t)s5*256 + l*4];
    uint2 r6=*(const uint2*)&h1[(size_t)s6*256 + l*4];
    uint2 r7=*(const uint2*)&h1[(size_t)s7*256 + l*4];
    acc4s(a,r0,1.f); acc4s(a,r1,1.f); acc4s(a,r2,1.f); acc4s(a,r3,1.f);
    acc4s(a,r4,1.f); acc4s(a,r5,1.f); acc4s(a,r6,1.f); acc4s(a,r7,1.f);
  }
  for(; e<e1; ++e){
    uint2 r=*(const uint2*)&h1[(size_t)srcs[e]*256 + l*4];
    acc4s(a,r,1.f);
  }
  uint2 o; o.x=pk2(a[0],a[1]); o.y=pk2(a[2],a[3]);
  *(uint2*)&z1[(size_t)node*256 + l*4] = o;
}

// ---------------------------------------------------------------------------
// K5a: GIN-2 aggregate, R15 = R13 loop (batch-4, 28 VGPR) + perm-ordered
// edges. One m-slice per block (slice pinned to XCD m&7). 4 waves x 8 nodes;
// lane: grp=l>>3 (node), q=l&7 (16B chunk). Stride-balanced sorted chunks
// (wave w of block g takes chunk w*512+g); the group's 8 nodes have
// CONTIGUOUS edge ranges in srcs. Unpredicated batch-4 to wave-min;
// predicated batch-1 tail. z2 row-major [node][m][d].
// ---------------------------------------------------------------------------
__global__ __launch_bounds__(256) void k_agg2(
  const u16* __restrict__ h2T, const float* __restrict__ eps2p,
  const int* __restrict__ offP, const int* __restrict__ srcs,
  const int* __restrict__ perm, u16* __restrict__ z2)
{
  const int t=threadIdx.x, l=t&63, w=t>>6;
  const int m = blockIdx.x & 15, g = blockIdx.x >> 4;   // g in [0,512)
  const int grp = l>>3, q = l&7;
  const int p = (w*512 + g)*8 + grp;                    // sorted position
  const int node = perm[p];
  const float epe = 1.f + eps2p[0];
  const u16* __restrict__ base = h2T + (size_t)m*(NSUM*DP);

  f32x2 A[4];
  {
    uint4 x = *(const uint4*)&base[(size_t)node*DP + q*8];
    f32x2 s2; s2.x=epe; s2.y=epe;
    A[0]=s2*up2(x.x); A[1]=s2*up2(x.y); A[2]=s2*up2(x.z); A[3]=s2*up2(x.w);
  }
  const int e0 = offP[p], e1 = offP[p+1];
  int dmin = e1 - e0, dmax = dmin;
  #pragma unroll
  for(int d=1; d<64; d<<=1){
    dmin = min(dmin, __shfl_xor(dmin, d, 64));
    dmax = max(dmax, __shfl_xor(dmax, d, 64));
  }
  const int dmin4 = dmin & ~3;

  int i = 0;
  // fast path: all 8 nodes in every lane-group have >= dmin edges.
  for(; i < dmin4; i += 4){
    int i0 = srcs[e0+i],   i1 = srcs[e0+i+1];
    int i2 = srcs[e0+i+2], i3 = srcs[e0+i+3];
    uint4 x0 = *(const uint4*)&base[(size_t)i0*DP + q*8];
    uint4 x1 = *(const uint4*)&base[(size_t)i1*DP + q*8];
    uint4 x2 = *(const uint4*)&base[(size_t)i2*DP + q*8];
    uint4 x3 = *(const uint4*)&base[(size_t)i3*DP + q*8];
    A[0]+=up2(x0.x); A[1]+=up2(x0.y); A[2]+=up2(x0.z); A[3]+=up2(x0.w);
    A[0]+=up2(x1.x); A[1]+=up2(x1.y); A[2]+=up2(x1.z); A[3]+=up2(x1.w);
    A[0]+=up2(x2.x); A[1]+=up2(x2.y); A[2]+=up2(x2.z); A[3]+=up2(x2.w);
    A[0]+=up2(x3.x); A[1]+=up2(x3.y); A[2]+=up2(x3.z); A[3]+=up2(x3.w);
  }
  // tail: dmin4..dmax, scale-predicated (masked lanes accumulate x0).
  for(; i < dmax; ++i){
    int pa = e0+i;
    float sa = (pa < e1) ? 1.f : 0.f;
    int ea = min(pa, NE-1);
    int ia = srcs[ea];
    uint4 xa = *(const uint4*)&base[(size_t)ia*DP + q*8];
    f32x2 va; va.x=sa; va.y=sa;
    A[0]+=va*up2(xa.x); A[1]+=va*up2(xa.y); A[2]+=va*up2(xa.z); A[3]+=va*up2(xa.w);
  }

  uint4 o;
  o.x=pk2(A[0].x,A[0].y); o.y=pk2(A[1].x,A[1].y);
  o.z=pk2(A[2].x,A[2].y); o.w=pk2(A[3].x,A[3].y);
  *(uint4*)&z2[(size_t)node*1024 + m*DP + q*8] = o;
}

// ---------------------------------------------------------------------------
// K4b: GIN-1 MLP via MFMA; writes h2 TRANSPOSED h2T[m][node][d]. (unchanged)
// ---------------------------------------------------------------------------
__global__ __launch_bounds__(256) void k_mm1(
  const u16* __restrict__ z1, const float* __restrict__ W1a, const float* __restrict__ b1a,
  const float* __restrict__ W1b, const float* __restrict__ b1b, u16* __restrict__ h2T)
{
  __shared__ float tS[4][16*68 + 4];
  const int t=threadIdx.x, l=t&63, w=t>>6;
  const int col=l&15, quad=l>>4;

  bf16x8 fa[4], fb[4][2];
  float bav[4], bbv[4];
  #pragma unroll
  for(int nt=0;nt<4;++nt){
    fa[nt]    = bfragW(W1a, HM, 0,  nt*16, col, quad);   // k>=16 zeroed
    fb[nt][0] = bfragW(W1b, DP, 0,  nt*16, col, quad);
    fb[nt][1] = bfragW(W1b, DP, 32, nt*16, col, quad);
    bav[nt] = b1a[nt*16+col];
    bbv[nt] = b1b[nt*16+col];
  }
  for(int ni=0;ni<2;++ni){
    const int node = blockIdx.x*8 + ni*4 + w;
    bf16x8 a0;
    #pragma unroll
    for(int j=0;j<8;++j) a0[j]=0;
    if (quad < 2) a0 = *(const bf16x8*)&z1[(size_t)node*256 + col*16 + quad*8];
    #pragma unroll
    for(int nt=0;nt<4;++nt){
      f32x4 c = {bav[nt], bav[nt], bav[nt], bav[nt]};
      c = MFMA16(a0, fa[nt], c);
      #pragma unroll
      for(int r=0;r<4;++r)
        tS[w][(quad*4+r)*68 + nt*16 + col] = fmaxf(c[r], 0.f);
    }
    bf16x8 ta0 = afragT(&tS[w][col*68 + quad*8]);
    bf16x8 ta1 = afragT(&tS[w][col*68 + 32 + quad*8]);
    #pragma unroll
    for(int nt=0;nt<4;++nt){
      f32x4 c = {bbv[nt], bbv[nt], bbv[nt], bbv[nt]};
      c = MFMA16(ta0, fb[nt][0], c);
      c = MFMA16(ta1, fb[nt][1], c);
      #pragma unroll
      for(int r=0;r<4;++r)
        h2T[((size_t)(quad*4+r)*NSUM + node)*DP + nt*16 + col] = f2b(fmaxf(c[r], 0.f));
    }
  }
}

// ---------------------------------------------------------------------------
// K5b: GIN-2 MLP via MFMA + ReLU + sum over M -> out f32 [NSUM,64]. (unchanged)
// ---------------------------------------------------------------------------
__global__ __launch_bounds__(256) void k_mm2(
  const u16* __restrict__ z2, const float* __restrict__ W2a, const float* __restrict__ b2a,
  const float* __restrict__ W2b, const float* __restrict__ b2b, float* __restrict__ out)
{
  __shared__ float tS[4][16*68 + 4];
  const int t=threadIdx.x, l=t&63, w=t>>6;
  const int col=l&15, quad=l>>4;

  bf16x8 fa[4][2], fb[4][2];
  float bav[4], bbv[4];
  #pragma unroll
  for(int nt=0;nt<4;++nt){
    fa[nt][0] = bfragW(W2a, DP, 0,  nt*16, col, quad);
    fa[nt][1] = bfragW(W2a, DP, 32, nt*16, col, quad);
    fb[nt][0] = bfragW(W2b, DP, 0,  nt*16, col, quad);
    fb[nt][1] = bfragW(W2b, DP, 32, nt*16, col, quad);
    bav[nt] = b2a[nt*16+col];
    bbv[nt] = b2b[nt*16+col];
  }
  for(int ni=0;ni<2;++ni){
    const int node = blockIdx.x*8 + ni*4 + w;
    const u16* zrow = &z2[(size_t)node*1024];
    bf16x8 a0 = *(const bf16x8*)&zrow[col*64 + quad*8];
    bf16x8 a1 = *(const bf16x8*)&zrow[col*64 + quad*8 + 32];
    #pragma unroll
    for(int nt=0;nt<4;++nt){
      f32x4 c = {bav[nt], bav[nt], bav[nt], bav[nt]};
      c = MFMA16(a0, fa[nt][0], c);
      c = MFMA16(a1, fa[nt][1], c);
      #pragma unroll
      for(int r=0;r<4;++r)
        tS[w][(quad*4+r)*68 + nt*16 + col] = fmaxf(c[r], 0.f);
    }
    bf16x8 ta0 = afragT(&tS[w][col*68 + quad*8]);
    bf16x8 ta1 = afragT(&tS[w][col*68 + 32 + quad*8]);
    #pragma unroll
    for(int nt=0;nt<4;++nt){
      f32x4 c = {bbv[nt], bbv[nt], bbv[nt], bbv[nt]};
      c = MFMA16(ta0, fb[nt][0], c);
      c = MFMA16(ta1, fb[nt][1], c);
      float s = fmaxf(c[0],0.f)+fmaxf(c[1],0.f)+fmaxf(c[2],0.f)+fmaxf(c[3],0.f);
      s += __shfl_xor(s, 16, 64);
      s += __shfl_xor(s, 32, 64);
      if (quad == 0)
        out[(size_t)node*64 + nt*16 + col] = s;
    }
  }
}

extern "C" void kernel_launch(void* const* d_in, const int* in_sizes, int n_in,
                              void* d_out, int out_size, void* d_ws, size_t ws_size,
                              hipStream_t stream)
{
  (void)in_sizes; (void)n_in; (void)out_size; (void)ws_size;
  const float* lap  = (const float*)d_in[0];
  const float* W0   = (const float*)d_in[1];
  const float* mlpW = (const float*)d_in[2];
  // d_in[3] = mlp_b: cancels inside BatchNorm (pure mean shift)
  const float* bng  = (const float*)d_in[4];
  const float* bnb  = (const float*)d_in[5];
  const float* eps1 = (const float*)d_in[6];
  const float* W1a  = (const float*)d_in[7];
  const float* b1a  = (const float*)d_in[8];
  const float* W1b  = (const float*)d_in[9];
  const float* b1b  = (const float*)d_in[10];
  const float* eps2 = (const float*)d_in[11];
  const float* W2a  = (const float*)d_in[12];
  const float* b2a  = (const float*)d_in[13];
  const float* W2b  = (const float*)d_in[14];
  const float* b2b  = (const float*)d_in[15];
  const int*   ei   = (const int*)d_in[16];
  const int* srcI = ei;
  const int* dstI = ei + NE;

  char* ws = (char*)d_ws;
  u16* h1   = (u16*)(ws);                    //  8,388,608 B  [16384][16][16]
  u16* z1   = (u16*)(ws + 8388608);          //  8,388,608 B
  u16* h2T  = (u16*)(ws + 16777216);         // 33,554,432 B  [16][16384][64]
  u16* z2   = (u16*)(ws + 50331648);         // 33,554,432 B  [16384][16][64]
  int* cntw = (int*)(ws + 83886080);         //     65,536 B  cnt, then wpos
  int* offP = (int*)(ws + 83951616);         //     65,792 B  sorted edge offs
  int* perm = (int*)(ws + 84017408);         //     65,536 B  degree-sort perm
  int* srcs = (int*)(ws + 84082944);         //  1,048,576 B  perm-ordered edges

  k_poly   <<<BG,      256, 0, stream>>>(lap, W0, mlpW, bng, bnb, h1, cntw);
  k_hist   <<<NE/256,  256, 0, stream>>>(dstI, cntw);
  k_perm   <<<1,      1024, 0, stream>>>(cntw, perm, offP);
  k_scatter<<<NE/256,  256, 0, stream>>>(srcI, dstI, cntw, srcs);
  k_agg1   <<<NSUM/4,  256, 0, stream>>>(h1, eps1, offP, perm, srcs, z1);
  k_mm1    <<<NSUM/8,  256, 0, stream>>>(z1, W1a, b1a, W1b, b1b, h2T);
  k_agg2   <<<16*(NSUM/32), 256, 0, stream>>>(h2T, eps2, offP, srcs, perm, z2);
  k_mm2    <<<NSUM/8,  256, 0, stream>>>(z2, W2a, b2a, W2b, b2b, (float*)d_out);
}

// Round 10
// 233.630 us; speedup vs baseline: 1.1243x; 1.0633x over previous
//
#include <hip/hip_runtime.h>

typedef unsigned short u16;
typedef unsigned int   u32;
typedef short bf16x8 __attribute__((ext_vector_type(8)));
typedef float f32x4  __attribute__((ext_vector_type(4)));
typedef float f32x2  __attribute__((ext_vector_type(2)));

#define BG    128      // graphs
#define NN    128      // nodes per graph
#define MS    16       // samples
#define KP    8        // pearl_k
#define HM    16       // mlp hidden
#define DP    64       // pe dims
#define NSUM  16384    // BG*NN
#define NE    262144   // edges
#define SITES 2048     // NN*MS

// R11: agg2 m-sliced, persistent chunk ownership (53.6us agg2, 259 total).
// R12: degree-sort good; m/m+8 fusion = L2 thrash.
// R13: batch-4 + sort: agg2 44.1us; single-block perm ate the win.
// R14: batch-8 shfl REGRESSED (VGPR 28->48). Reverted.
// R15: perm-ordered edge array free from counting sort (offP = ebase[b]+j*b),
//   k_scan deleted, streaming edge reads: total 248.4us (best). Top-5
//   dispatches now harness fills (~44us) -> all our kernels < 44us.
// R16 (this round): mm1/mm2 weight-preload amortization. Each thread
//   rebuilds ~104-136 scalar-load weight fragments per block; at 2048 blocks
//   that's ~500MB of L2 traffic + latency-serial preamble repeated 2048x.
//   ni 2->8 (32 nodes/block, grid NSUM/32=512): preload amortized 4x.
//   Everything else frozen at R15.

__device__ __forceinline__ float blo(u32 u){ union{u32 i; float f;} v; v.i=u<<16; return v.f; }
__device__ __forceinline__ float bhi(u32 u){ union{u32 i; float f;} v; v.i=u&0xffff0000u; return v.f; }
__device__ __forceinline__ u16  f2b(float f){ union{float f; u32 i;} v; v.f=f; u32 x=v.i; x += 0x7fffu + ((x>>16)&1u); return (u16)(x>>16); }
__device__ __forceinline__ u32  pk2(float a, float b){ return (u32)f2b(a) | ((u32)f2b(b)<<16); }
__device__ __forceinline__ f32x2 up2(u32 u){ f32x2 v; v.x=blo(u); v.y=bhi(u); return v; }

__device__ __forceinline__ void fsplit(float x, short& hi, short& lo){
  u16 h = f2b(x); hi = (short)h; lo = (short)f2b(x - blo((u32)h));
}

__device__ __forceinline__ void acc4s(float* a, uint2 x, float s){
  a[0]+=s*blo(x.x); a[1]+=s*bhi(x.x); a[2]+=s*blo(x.y); a[3]+=s*bhi(x.y);
}

#define MFMA16(a,b,c) __builtin_amdgcn_mfma_f32_16x16x32_bf16(a,b,c,0,0,0)

__device__ __forceinline__ bf16x8 bfragW(const float* __restrict__ W, int nrows,
                                         int k0, int nb, int col, int quad){
  bf16x8 f;
  #pragma unroll
  for(int j=0;j<8;++j){
    int k = k0 + quad*8 + j;
    float v = (k < nrows) ? W[k*DP + nb + col] : 0.f;
    f[j] = (short)f2b(v);
  }
  return f;
}
__device__ __forceinline__ bf16x8 afragT(const float* tp){
  float4 v0 = *(const float4*)tp;
  float4 v1 = *(const float4*)(tp+4);
  bf16x8 a;
  a[0]=(short)f2b(v0.x); a[1]=(short)f2b(v0.y); a[2]=(short)f2b(v0.z); a[3]=(short)f2b(v0.w);
  a[4]=(short)f2b(v1.x); a[5]=(short)f2b(v1.y); a[6]=(short)f2b(v1.z); a[7]=(short)f2b(v1.w);
  return a;
}

// ---------------------------------------------------------------------------
// K1: poly filter via MFMA split-precision (R10, unchanged).
// ---------------------------------------------------------------------------
__global__ __launch_bounds__(256,1) void k_poly(
    const float* __restrict__ lap, const float* __restrict__ W0, const float* __restrict__ mlpW,
    const float* __restrict__ bng, const float* __restrict__ bnb, u16* __restrict__ h1,
    int* __restrict__ cnt)
{
  __shared__ float Wbuf[2][SITES];
  __shared__ float mlpWS[KP*HM];
  __shared__ float red[4][32];
  __shared__ float stat[32];
  __shared__ float ssc[HM], ssh[HM];

  const int b = blockIdx.x, t = threadIdx.x, l = t&63, w = t>>6;
  const int col = l&15, quad = l>>4;
  if (t < 128) cnt[b*128 + t] = 0;

  {
    const float4* src = (const float4*)(W0 + (size_t)b*SITES);
    for (int i=t; i<SITES/4; i+=256) ((float4*)Wbuf[0])[i] = src[i];
    if (t < KP*HM) mlpWS[t] = mlpW[t];
  }

  bf16x8 Ah[2][4], Al[2][4];
  {
    const float* lg = lap + (size_t)b*NN*NN;
    #pragma unroll
    for(int Mt=0;Mt<2;++Mt){
      const int nr = w*32 + Mt*16 + col;
      #pragma unroll
      for(int Kc=0;Kc<4;++Kc){
        const float* p = lg + (size_t)nr*NN + Kc*32 + quad*8;
        float4 v0 = *(const float4*)p;
        float4 v1 = *(const float4*)(p+4);
        float xs[8] = {v0.x,v0.y,v0.z,v0.w,v1.x,v1.y,v1.z,v1.w};
        #pragma unroll
        for(int j=0;j<8;++j){ short hi,lo; fsplit(xs[j],hi,lo); Ah[Mt][Kc][j]=hi; Al[Mt][Kc][j]=lo; }
      }
    }
  }

  float h[8][16];
  {
    const float* w0g = W0 + (size_t)b*SITES;
    #pragma unroll
    for(int Mt=0;Mt<2;++Mt){
      #pragma unroll
      for(int r=0;r<4;++r){
        const int n = w*32 + Mt*16 + quad*4 + r;
        float sv = w0g[n*MS + col];
        #pragma unroll
        for(int c=0;c<16;++c) h[Mt*4+r][c] = sv*mlpW[c];
      }
    }
  }
  __syncthreads();

  int cur=0;
  for(int k=1;k<KP;++k){
    f32x4 c0 = {0.f,0.f,0.f,0.f};
    f32x4 c1 = {0.f,0.f,0.f,0.f};
    #pragma unroll
    for(int Kc=0;Kc<4;++Kc){
      const float* wb = &Wbuf[cur][(Kc*32 + quad*8)*MS + col];
      bf16x8 Bh, Bl;
      #pragma unroll
      for(int j=0;j<8;++j){
        float x = wb[j*MS];
        short hi,lo; fsplit(x,hi,lo); Bh[j]=hi; Bl[j]=lo;
      }
      c0 = MFMA16(Ah[0][Kc], Bh, c0);
      c0 = MFMA16(Ah[0][Kc], Bl, c0);
      c0 = MFMA16(Al[0][Kc], Bh, c0);
      c1 = MFMA16(Ah[1][Kc], Bh, c1);
      c1 = MFMA16(Ah[1][Kc], Bl, c1);
      c1 = MFMA16(Al[1][Kc], Bh, c1);
    }
    float mw[16];
    #pragma unroll
    for(int c=0;c<16;++c) mw[c]=mlpWS[k*16+c];
    #pragma unroll
    for(int r=0;r<4;++r){
      const int n0 = w*32 + quad*4 + r;
      Wbuf[cur^1][n0*MS + col]        = c0[r];
      Wbuf[cur^1][(n0+16)*MS + col]   = c1[r];
      #pragma unroll
      for(int c=0;c<16;++c){ h[r][c] += c0[r]*mw[c]; h[4+r][c] += c1[r]*mw[c]; }
    }
    __syncthreads();
    cur ^= 1;
  }

  float sum[16], sq[16];
  #pragma unroll
  for(int c=0;c<16;++c){ sum[c]=0.f; sq[c]=0.f; }
  #pragma unroll
  for(int s=0;s<8;++s){
    #pragma unroll
    for(int c=0;c<16;++c){ float v=h[s][c]; sum[c]+=v; sq[c]+=v*v; }
  }
  #pragma unroll
  for(int d=1;d<64;d<<=1){
    #pragma unroll
    for(int c=0;c<16;++c){ sum[c]+=__shfl_xor(sum[c],d,64); sq[c]+=__shfl_xor(sq[c],d,64); }
  }
  if(l==0){
    #pragma unroll
    for(int c=0;c<16;++c){ red[w][c]=sum[c]; red[w][16+c]=sq[c]; }
  }
  __syncthreads();
  if(t<32) stat[t]=red[0][t]+red[1][t]+red[2][t]+red[3][t];
  __syncthreads();
  if(t<16){
    float mu  = stat[t]*(1.f/SITES);
    float var = stat[16+t]*(1.f/SITES) - mu*mu;
    float sc  = bng[t] * rsqrtf(var + 1e-5f);
    ssc[t]=sc; ssh[t]=bnb[t] - mu*sc;
  }
  __syncthreads();
  {
    float sc[16], sh[16];
    #pragma unroll
    for(int c=0;c<16;++c){ sc[c]=ssc[c]; sh[c]=ssh[c]; }
    #pragma unroll
    for(int s=0;s<8;++s){
      const int n = w*32 + (s>>2)*16 + quad*4 + (s&3);
      const int node = b*NN + n;
      float r[16];
      #pragma unroll
      for(int c=0;c<16;++c) r[c]=fmaxf(h[s][c]*sc[c]+sh[c], 0.f);
      uint4 A;
      A.x=pk2(r[0],r[1]);  A.y=pk2(r[2],r[3]);  A.z=pk2(r[4],r[5]);  A.w=pk2(r[6],r[7]);
      uint4 Bv;
      Bv.x=pk2(r[8],r[9]); Bv.y=pk2(r[10],r[11]); Bv.z=pk2(r[12],r[13]); Bv.w=pk2(r[14],r[15]);
      u16* o = h1 + (size_t)node*256 + (size_t)col*HM;
      *(uint4*)o     = A;
      *(uint4*)(o+8) = Bv;
    }
  }
}

// --------------------------- CSR build (by dst) ----------------------------
__global__ void k_hist(const int* __restrict__ dst, int* __restrict__ cnt){
  int e = blockIdx.x*256 + threadIdx.x;
  atomicAdd(&cnt[dst[e]], 1);
}

// ---------------------------------------------------------------------------
// K-perm R15: counting sort by degree (64 bins) that ALSO emits perm-ordered
// edge offsets for free (all nodes in bin b have degree exactly b, so the
// j-th node of bin b starts at ebase[b] + j*b). Outputs perm, offP, and
// scatter cursors (cntw in place). Per-wave sub-histograms. (unchanged)
// ---------------------------------------------------------------------------
__global__ __launch_bounds__(1024) void k_perm(int* cntw, int* __restrict__ perm,
                                               int* __restrict__ offP){
  __shared__ int hist[16][64];
  __shared__ int base[64];
  __shared__ int ebase[64];
  __shared__ int wbase[16][64];
  const int t = threadIdx.x, w = t>>6, l = t&63;
  hist[w][l] = 0;                       // 16x64 = 1024 = blockDim
  __syncthreads();

  int mybin[16];
  #pragma unroll
  for (int i=0;i<16;++i){
    int n = i*1024 + t;                 // coalesced over cnt
    int b = min(cntw[n], 63);
    mybin[i] = b;
    atomicAdd(&hist[w][b], 1);          // within-wave contention only
  }
  __syncthreads();

  if (w == 0){                          // lane l = bin l: dual shfl scan
    int s = 0;
    #pragma unroll
    for (int k=0;k<16;++k) s += hist[k][l];
    int se = s * l;                     // edges in bin l
    int v = s, ve = se;
    #pragma unroll
    for (int d=1; d<64; d<<=1){
      int u  = __shfl_up(v,  d, 64);
      int ue = __shfl_up(ve, d, 64);
      if (l >= d){ v += u; ve += ue; }
    }
    base[l]  = v  - s;                  // exclusive node-space
    ebase[l] = ve - se;                 // exclusive edge-space
  }
  __syncthreads();

  if (w == 1){                          // per-wave placement bases for bin l
    int run = base[l];
    #pragma unroll
    for (int k=0;k<16;++k){ wbase[k][l] = run; run += hist[k][l]; }
  }
  __syncthreads();

  #pragma unroll
  for (int i=0;i<16;++i){
    int b    = mybin[i];
    int pos  = atomicAdd(&wbase[w][b], 1);
    int node = i*1024 + t;
    int e0   = ebase[b] + (pos - base[b]) * b;
    perm[pos] = node;
    offP[pos] = e0;
    cntw[node] = e0;                    // scatter cursor (wpos)
  }
  if (t == 0) offP[NSUM] = NE;
}

__global__ void k_scatter(const int* __restrict__ srcI, const int* __restrict__ dstI,
                          int* __restrict__ wpos, int* __restrict__ srcs){
  int e = blockIdx.x*256 + threadIdx.x;
  int p = atomicAdd(&wpos[dstI[e]], 1);
  srcs[p] = srcI[e];
}

// ---------------------------------------------------------------------------
// K4a: GIN-1 aggregate, sorted-position-indexed. (unchanged from R15)
// ---------------------------------------------------------------------------
__global__ __launch_bounds__(256) void k_agg1(
  const u16* __restrict__ h1, const float* __restrict__ eps1p,
  const int* __restrict__ offP, const int* __restrict__ perm,
  const int* __restrict__ srcs, u16* __restrict__ z1)
{
  const int t=threadIdx.x, l=t&63;
  const int p = blockIdx.x*4 + (t>>6);
  const int node = perm[p];
  const float epe = 1.f + eps1p[0];
  float a[4] = {0.f,0.f,0.f,0.f};
  acc4s(a, *(const uint2*)&h1[(size_t)node*256 + l*4], epe);
  int e = offP[p]; const int e1 = offP[p+1];
  for(; e+8<=e1; e+=8){
    int s0=srcs[e],s1=srcs[e+1],s2=srcs[e+2],s3=srcs[e+3];
    int s4=srcs[e+4],s5=srcs[e+5],s6=srcs[e+6],s7=srcs[e+7];
    uint2 r0=*(const uint2*)&h1[(size_t)s0*256 + l*4];
    uint2 r1=*(const uint2*)&h1[(size_t)s1*256 + l*4];
    uint2 r2=*(const uint2*)&h1[(size_t)s2*256 + l*4];
    uint2 r3=*(const uint2*)&h1[(size_t)s3*256 + l*4];
    uint2 r4=*(const uint2*)&h1[(size_t)s4*256 + l*4];
    uint2 r5=*(const uint2*)&h1[(size_t)s5*256 + l*4];
    uint2 r6=*(const uint2*)&h1[(size_t)s6*256 + l*4];
    uint2 r7=*(const uint2*)&h1[(size_t)s7*256 + l*4];
    acc4s(a,r0,1.f); acc4s(a,r1,1.f); acc4s(a,r2,1.f); acc4s(a,r3,1.f);
    acc4s(a,r4,1.f); acc4s(a,r5,1.f); acc4s(a,r6,1.f); acc4s(a,r7,1.f);
  }
  for(; e<e1; ++e){
    uint2 r=*(const uint2*)&h1[(size_t)srcs[e]*256 + l*4];
    acc4s(a,r,1.f);
  }
  uint2 o; o.x=pk2(a[0],a[1]); o.y=pk2(a[2],a[3]);
  *(uint2*)&z1[(size_t)node*256 + l*4] = o;
}

// ---------------------------------------------------------------------------
// K5a: GIN-2 aggregate. (unchanged from R15: batch-4, perm-ordered edges,
// one m-slice per block, stride-balanced sorted chunks)
// ---------------------------------------------------------------------------
__global__ __launch_bounds__(256) void k_agg2(
  const u16* __restrict__ h2T, const float* __restrict__ eps2p,
  const int* __restrict__ offP, const int* __restrict__ srcs,
  const int* __restrict__ perm, u16* __restrict__ z2)
{
  const int t=threadIdx.x, l=t&63, w=t>>6;
  const int m = blockIdx.x & 15, g = blockIdx.x >> 4;   // g in [0,512)
  const int grp = l>>3, q = l&7;
  const int p = (w*512 + g)*8 + grp;                    // sorted position
  const int node = perm[p];
  const float epe = 1.f + eps2p[0];
  const u16* __restrict__ base = h2T + (size_t)m*(NSUM*DP);

  f32x2 A[4];
  {
    uint4 x = *(const uint4*)&base[(size_t)node*DP + q*8];
    f32x2 s2; s2.x=epe; s2.y=epe;
    A[0]=s2*up2(x.x); A[1]=s2*up2(x.y); A[2]=s2*up2(x.z); A[3]=s2*up2(x.w);
  }
  const int e0 = offP[p], e1 = offP[p+1];
  int dmin = e1 - e0, dmax = dmin;
  #pragma unroll
  for(int d=1; d<64; d<<=1){
    dmin = min(dmin, __shfl_xor(dmin, d, 64));
    dmax = max(dmax, __shfl_xor(dmax, d, 64));
  }
  const int dmin4 = dmin & ~3;

  int i = 0;
  // fast path: all 8 nodes in every lane-group have >= dmin edges.
  for(; i < dmin4; i += 4){
    int i0 = srcs[e0+i],   i1 = srcs[e0+i+1];
    int i2 = srcs[e0+i+2], i3 = srcs[e0+i+3];
    uint4 x0 = *(const uint4*)&base[(size_t)i0*DP + q*8];
    uint4 x1 = *(const uint4*)&base[(size_t)i1*DP + q*8];
    uint4 x2 = *(const uint4*)&base[(size_t)i2*DP + q*8];
    uint4 x3 = *(const uint4*)&base[(size_t)i3*DP + q*8];
    A[0]+=up2(x0.x); A[1]+=up2(x0.y); A[2]+=up2(x0.z); A[3]+=up2(x0.w);
    A[0]+=up2(x1.x); A[1]+=up2(x1.y); A[2]+=up2(x1.z); A[3]+=up2(x1.w);
    A[0]+=up2(x2.x); A[1]+=up2(x2.y); A[2]+=up2(x2.z); A[3]+=up2(x2.w);
    A[0]+=up2(x3.x); A[1]+=up2(x3.y); A[2]+=up2(x3.z); A[3]+=up2(x3.w);
  }
  // tail: dmin4..dmax, scale-predicated (masked lanes accumulate x0).
  for(; i < dmax; ++i){
    int pa = e0+i;
    float sa = (pa < e1) ? 1.f : 0.f;
    int ea = min(pa, NE-1);
    int ia = srcs[ea];
    uint4 xa = *(const uint4*)&base[(size_t)ia*DP + q*8];
    f32x2 va; va.x=sa; va.y=sa;
    A[0]+=va*up2(xa.x); A[1]+=va*up2(xa.y); A[2]+=va*up2(xa.z); A[3]+=va*up2(xa.w);
  }

  uint4 o;
  o.x=pk2(A[0].x,A[0].y); o.y=pk2(A[1].x,A[1].y);
  o.z=pk2(A[2].x,A[2].y); o.w=pk2(A[3].x,A[3].y);
  *(uint4*)&z2[(size_t)node*1024 + m*DP + q*8] = o;
}

// ---------------------------------------------------------------------------
// K4b: GIN-1 MLP via MFMA; writes h2T[m][node][d]. R16: 32 nodes/block
// (ni<8, grid NSUM/32) — weight-fragment preload amortized 4x.
// ---------------------------------------------------------------------------
__global__ __launch_bounds__(256) void k_mm1(
  const u16* __restrict__ z1, const float* __restrict__ W1a, const float* __restrict__ b1a,
  const float* __restrict__ W1b, const float* __restrict__ b1b, u16* __restrict__ h2T)
{
  __shared__ float tS[4][16*68 + 4];
  const int t=threadIdx.x, l=t&63, w=t>>6;
  const int col=l&15, quad=l>>4;

  bf16x8 fa[4], fb[4][2];
  float bav[4], bbv[4];
  #pragma unroll
  for(int nt=0;nt<4;++nt){
    fa[nt]    = bfragW(W1a, HM, 0,  nt*16, col, quad);   // k>=16 zeroed
    fb[nt][0] = bfragW(W1b, DP, 0,  nt*16, col, quad);
    fb[nt][1] = bfragW(W1b, DP, 32, nt*16, col, quad);
    bav[nt] = b1a[nt*16+col];
    bbv[nt] = b1b[nt*16+col];
  }
  for(int ni=0;ni<8;++ni){
    const int node = blockIdx.x*32 + ni*4 + w;
    bf16x8 a0;
    #pragma unroll
    for(int j=0;j<8;++j) a0[j]=0;
    if (quad < 2) a0 = *(const bf16x8*)&z1[(size_t)node*256 + col*16 + quad*8];
    #pragma unroll
    for(int nt=0;nt<4;++nt){
      f32x4 c = {bav[nt], bav[nt], bav[nt], bav[nt]};
      c = MFMA16(a0, fa[nt], c);
      #pragma unroll
      for(int r=0;r<4;++r)
        tS[w][(quad*4+r)*68 + nt*16 + col] = fmaxf(c[r], 0.f);
    }
    bf16x8 ta0 = afragT(&tS[w][col*68 + quad*8]);
    bf16x8 ta1 = afragT(&tS[w][col*68 + 32 + quad*8]);
    #pragma unroll
    for(int nt=0;nt<4;++nt){
      f32x4 c = {bbv[nt], bbv[nt], bbv[nt], bbv[nt]};
      c = MFMA16(ta0, fb[nt][0], c);
      c = MFMA16(ta1, fb[nt][1], c);
      #pragma unroll
      for(int r=0;r<4;++r)
        h2T[((size_t)(quad*4+r)*NSUM + node)*DP + nt*16 + col] = f2b(fmaxf(c[r], 0.f));
    }
  }
}

// ---------------------------------------------------------------------------
// K5b: GIN-2 MLP via MFMA + ReLU + sum over M -> out f32 [NSUM,64].
// R16: 32 nodes/block (ni<8, grid NSUM/32) — preload amortized 4x.
// ---------------------------------------------------------------------------
__global__ __launch_bounds__(256) void k_mm2(
  const u16* __restrict__ z2, const float* __restrict__ W2a, const float* __restrict__ b2a,
  const float* __restrict__ W2b, const float* __restrict__ b2b, float* __restrict__ out)
{
  __shared__ float tS[4][16*68 + 4];
  const int t=threadIdx.x, l=t&63, w=t>>6;
  const int col=l&15, quad=l>>4;

  bf16x8 fa[4][2], fb[4][2];
  float bav[4], bbv[4];
  #pragma unroll
  for(int nt=0;nt<4;++nt){
    fa[nt][0] = bfragW(W2a, DP, 0,  nt*16, col, quad);
    fa[nt][1] = bfragW(W2a, DP, 32, nt*16, col, quad);
    fb[nt][0] = bfragW(W2b, DP, 0,  nt*16, col, quad);
    fb[nt][1] = bfragW(W2b, DP, 32, nt*16, col, quad);
    bav[nt] = b2a[nt*16+col];
    bbv[nt] = b2b[nt*16+col];
  }
  for(int ni=0;ni<8;++ni){
    const int node = blockIdx.x*32 + ni*4 + w;
    const u16* zrow = &z2[(size_t)node*1024];
    bf16x8 a0 = *(const bf16x8*)&zrow[col*64 + quad*8];
    bf16x8 a1 = *(const bf16x8*)&zrow[col*64 + quad*8 + 32];
    #pragma unroll
    for(int nt=0;nt<4;++nt){
      f32x4 c = {bav[nt], bav[nt], bav[nt], bav[nt]};
      c = MFMA16(a0, fa[nt][0], c);
      c = MFMA16(a1, fa[nt][1], c);
      #pragma unroll
      for(int r=0;r<4;++r)
        tS[w][(quad*4+r)*68 + nt*16 + col] = fmaxf(c[r], 0.f);
    }
    bf16x8 ta0 = afragT(&tS[w][col*68 + quad*8]);
    bf16x8 ta1 = afragT(&tS[w][col*68 + 32 + quad*8]);
    #pragma unroll
    for(int nt=0;nt<4;++nt){
      f32x4 c = {bbv[nt], bbv[nt], bbv[nt], bbv[nt]};
      c = MFMA16(ta0, fb[nt][0], c);
      c = MFMA16(ta1, fb[nt][1], c);
      float s = fmaxf(c[0],0.f)+fmaxf(c[1],0.f)+fmaxf(c[2],0.f)+fmaxf(c[3],0.f);
      s += __shfl_xor(s, 16, 64);
      s += __shfl_xor(s, 32, 64);
      if (quad == 0)
        out[(size_t)node*64 + nt*16 + col] = s;
    }
  }
}

extern "C" void kernel_launch(void* const* d_in, const int* in_sizes, int n_in,
                              void* d_out, int out_size, void* d_ws, size_t ws_size,
                              hipStream_t stream)
{
  (void)in_sizes; (void)n_in; (void)out_size; (void)ws_size;
  const float* lap  = (const float*)d_in[0];
  const float* W0   = (const float*)d_in[1];
  const float* mlpW = (const float*)d_in[2];
  // d_in[3] = mlp_b: cancels inside BatchNorm (pure mean shift)
  const float* bng  = (const float*)d_in[4];
  const float* bnb  = (const float*)d_in[5];
  const float* eps1 = (const float*)d_in[6];
  const float* W1a  = (const float*)d_in[7];
  const float* b1a  = (const float*)d_in[8];
  const float* W1b  = (const float*)d_in[9];
  const float* b1b  = (const float*)d_in[10];
  const float* eps2 = (const float*)d_in[11];
  const float* W2a  = (const float*)d_in[12];
  const float* b2a  = (const float*)d_in[13];
  const float* W2b  = (const float*)d_in[14];
  const float* b2b  = (const float*)d_in[15];
  const int*   ei   = (const int*)d_in[16];
  const int* srcI = ei;
  const int* dstI = ei + NE;

  char* ws = (char*)d_ws;
  u16* h1   = (u16*)(ws);                    //  8,388,608 B  [16384][16][16]
  u16* z1   = (u16*)(ws + 8388608);          //  8,388,608 B
  u16* h2T  = (u16*)(ws + 16777216);         // 33,554,432 B  [16][16384][64]
  u16* z2   = (u16*)(ws + 50331648);         // 33,554,432 B  [16384][16][64]
  int* cntw = (int*)(ws + 83886080);         //     65,536 B  cnt, then wpos
  int* offP = (int*)(ws + 83951616);         //     65,792 B  sorted edge offs
  int* perm = (int*)(ws + 84017408);         //     65,536 B  degree-sort perm
  int* srcs = (int*)(ws + 84082944);         //  1,048,576 B  perm-ordered edges

  k_poly   <<<BG,      256, 0, stream>>>(lap, W0, mlpW, bng, bnb, h1, cntw);
  k_hist   <<<NE/256,  256, 0, stream>>>(dstI, cntw);
  k_perm   <<<1,      1024, 0, stream>>>(cntw, perm, offP);
  k_scatter<<<NE/256,  256, 0, stream>>>(srcI, dstI, cntw, srcs);
  k_agg1   <<<NSUM/4,  256, 0, stream>>>(h1, eps1, offP, perm, srcs, z1);
  k_mm1    <<<NSUM/32, 256, 0, stream>>>(z1, W1a, b1a, W1b, b1b, h2T);
  k_agg2   <<<16*(NSUM/32), 256, 0, stream>>>(h2T, eps2, offP, srcs, perm, z2);
  k_mm2    <<<NSUM/32, 256, 0, stream>>>(z2, W2a, b2a, W2b, b2b, (float*)d_out);
}

// Round 11
// 227.985 us; speedup vs baseline: 1.1522x; 1.0248x over previous
//
#include <hip/hip_runtime.h>

typedef unsigned short u16;
typedef unsigned int   u32;
typedef short bf16x8 __attribute__((ext_vector_type(8)));
typedef float f32x4  __attribute__((ext_vector_type(4)));
typedef float f32x2  __attribute__((ext_vector_type(2)));

#define BG    128      // graphs
#define NN    128      // nodes per graph
#define MS    16       // samples
#define KP    8        // pearl_k
#define HM    16       // mlp hidden
#define DP    64       // pe dims
#define NSUM  16384    // BG*NN
#define NE    262144   // edges
#define SITES 2048     // NN*MS

// R11: agg2 m-sliced, persistent chunk ownership (53.6us agg2, 259 total).
// R12: degree-sort good; m/m+8 fusion = L2 thrash.
// R13: batch-4 + sort: agg2 44.1us; single-block perm ate the win.
// R14: batch-8 shfl REGRESSED (VGPR 28->48). Reverted.
// R15: perm-ordered edge array free from counting sort, k_scan deleted:
//   248.4us.
// R16: mm1/mm2 32 nodes/block (preload amortized 4x): 233.6us (best).
//   agg2 41.2us / FETCH 60.8MB; all other kernels < 41us.
// R17 (this round): k_poly packed-split Wbuf. The K-loop B-fragments
//   depend only on (Kc,quad,col,j) -> all 4 waves fsplit IDENTICAL values
//   from Wbuf floats (32 fsplits/thread/iter, 4x redundant, serial
//   x-blo(f2b(x)) chain). Now Wbuf holds u32 = (hi_bf16<<16)|lo_bf16:
//   writer fsplits once at write-back (8/thread/iter), readers unpack with
//   2 shift/mask ops. Numerically identical. Poly-only change.

__device__ __forceinline__ float blo(u32 u){ union{u32 i; float f;} v; v.i=u<<16; return v.f; }
__device__ __forceinline__ float bhi(u32 u){ union{u32 i; float f;} v; v.i=u&0xffff0000u; return v.f; }
__device__ __forceinline__ u16  f2b(float f){ union{float f; u32 i;} v; v.f=f; u32 x=v.i; x += 0x7fffu + ((x>>16)&1u); return (u16)(x>>16); }
__device__ __forceinline__ u32  pk2(float a, float b){ return (u32)f2b(a) | ((u32)f2b(b)<<16); }
__device__ __forceinline__ f32x2 up2(u32 u){ f32x2 v; v.x=blo(u); v.y=bhi(u); return v; }

__device__ __forceinline__ void fsplit(float x, short& hi, short& lo){
  u16 h = f2b(x); hi = (short)h; lo = (short)f2b(x - blo((u32)h));
}
// pack hi/lo split of x into one u32: (hi<<16)|lo
__device__ __forceinline__ u32 pksplit(float x){
  short hi, lo; fsplit(x, hi, lo);
  return ((u32)(u16)hi << 16) | (u32)(u16)lo;
}

__device__ __forceinline__ void acc4s(float* a, uint2 x, float s){
  a[0]+=s*blo(x.x); a[1]+=s*bhi(x.x); a[2]+=s*blo(x.y); a[3]+=s*bhi(x.y);
}

#define MFMA16(a,b,c) __builtin_amdgcn_mfma_f32_16x16x32_bf16(a,b,c,0,0,0)

__device__ __forceinline__ bf16x8 bfragW(const float* __restrict__ W, int nrows,
                                         int k0, int nb, int col, int quad){
  bf16x8 f;
  #pragma unroll
  for(int j=0;j<8;++j){
    int k = k0 + quad*8 + j;
    float v = (k < nrows) ? W[k*DP + nb + col] : 0.f;
    f[j] = (short)f2b(v);
  }
  return f;
}
__device__ __forceinline__ bf16x8 afragT(const float* tp){
  float4 v0 = *(const float4*)tp;
  float4 v1 = *(const float4*)(tp+4);
  bf16x8 a;
  a[0]=(short)f2b(v0.x); a[1]=(short)f2b(v0.y); a[2]=(short)f2b(v0.z); a[3]=(short)f2b(v0.w);
  a[4]=(short)f2b(v1.x); a[5]=(short)f2b(v1.y); a[6]=(short)f2b(v1.z); a[7]=(short)f2b(v1.w);
  return a;
}

// ---------------------------------------------------------------------------
// K1: poly filter via MFMA split-precision. R17: Wbuf holds packed hi/lo
// bf16 pairs (u32) — split once at write, unpack free at read.
// ---------------------------------------------------------------------------
__global__ __launch_bounds__(256,1) void k_poly(
    const float* __restrict__ lap, const float* __restrict__ W0, const float* __restrict__ mlpW,
    const float* __restrict__ bng, const float* __restrict__ bnb, u16* __restrict__ h1,
    int* __restrict__ cnt)
{
  __shared__ u32 Wbuf[2][SITES];
  __shared__ float mlpWS[KP*HM];
  __shared__ float red[4][32];
  __shared__ float stat[32];
  __shared__ float ssc[HM], ssh[HM];

  const int b = blockIdx.x, t = threadIdx.x, l = t&63, w = t>>6;
  const int col = l&15, quad = l>>4;
  if (t < 128) cnt[b*128 + t] = 0;

  {
    const float4* src = (const float4*)(W0 + (size_t)b*SITES);
    for (int i=t; i<SITES/4; i+=256){
      float4 v = src[i];
      uint4 pv;
      pv.x = pksplit(v.x); pv.y = pksplit(v.y);
      pv.z = pksplit(v.z); pv.w = pksplit(v.w);
      ((uint4*)Wbuf[0])[i] = pv;
    }
    if (t < KP*HM) mlpWS[t] = mlpW[t];
  }

  bf16x8 Ah[2][4], Al[2][4];
  {
    const float* lg = lap + (size_t)b*NN*NN;
    #pragma unroll
    for(int Mt=0;Mt<2;++Mt){
      const int nr = w*32 + Mt*16 + col;
      #pragma unroll
      for(int Kc=0;Kc<4;++Kc){
        const float* p = lg + (size_t)nr*NN + Kc*32 + quad*8;
        float4 v0 = *(const float4*)p;
        float4 v1 = *(const float4*)(p+4);
        float xs[8] = {v0.x,v0.y,v0.z,v0.w,v1.x,v1.y,v1.z,v1.w};
        #pragma unroll
        for(int j=0;j<8;++j){ short hi,lo; fsplit(xs[j],hi,lo); Ah[Mt][Kc][j]=hi; Al[Mt][Kc][j]=lo; }
      }
    }
  }

  float h[8][16];
  {
    const float* w0g = W0 + (size_t)b*SITES;
    #pragma unroll
    for(int Mt=0;Mt<2;++Mt){
      #pragma unroll
      for(int r=0;r<4;++r){
        const int n = w*32 + Mt*16 + quad*4 + r;
        float sv = w0g[n*MS + col];
        #pragma unroll
        for(int c=0;c<16;++c) h[Mt*4+r][c] = sv*mlpW[c];
      }
    }
  }
  __syncthreads();

  int cur=0;
  for(int k=1;k<KP;++k){
    f32x4 c0 = {0.f,0.f,0.f,0.f};
    f32x4 c1 = {0.f,0.f,0.f,0.f};
    #pragma unroll
    for(int Kc=0;Kc<4;++Kc){
      const u32* wb = &Wbuf[cur][(Kc*32 + quad*8)*MS + col];
      bf16x8 Bh, Bl;
      #pragma unroll
      for(int j=0;j<8;++j){
        u32 v = wb[j*MS];
        Bh[j] = (short)(v >> 16);
        Bl[j] = (short)(v & 0xffffu);
      }
      c0 = MFMA16(Ah[0][Kc], Bh, c0);
      c0 = MFMA16(Ah[0][Kc], Bl, c0);
      c0 = MFMA16(Al[0][Kc], Bh, c0);
      c1 = MFMA16(Ah[1][Kc], Bh, c1);
      c1 = MFMA16(Ah[1][Kc], Bl, c1);
      c1 = MFMA16(Al[1][Kc], Bh, c1);
    }
    float mw[16];
    #pragma unroll
    for(int c=0;c<16;++c) mw[c]=mlpWS[k*16+c];
    #pragma unroll
    for(int r=0;r<4;++r){
      const int n0 = w*32 + quad*4 + r;
      Wbuf[cur^1][n0*MS + col]        = pksplit(c0[r]);
      Wbuf[cur^1][(n0+16)*MS + col]   = pksplit(c1[r]);
      #pragma unroll
      for(int c=0;c<16;++c){ h[r][c] += c0[r]*mw[c]; h[4+r][c] += c1[r]*mw[c]; }
    }
    __syncthreads();
    cur ^= 1;
  }

  float sum[16], sq[16];
  #pragma unroll
  for(int c=0;c<16;++c){ sum[c]=0.f; sq[c]=0.f; }
  #pragma unroll
  for(int s=0;s<8;++s){
    #pragma unroll
    for(int c=0;c<16;++c){ float v=h[s][c]; sum[c]+=v; sq[c]+=v*v; }
  }
  #pragma unroll
  for(int d=1;d<64;d<<=1){
    #pragma unroll
    for(int c=0;c<16;++c){ sum[c]+=__shfl_xor(sum[c],d,64); sq[c]+=__shfl_xor(sq[c],d,64); }
  }
  if(l==0){
    #pragma unroll
    for(int c=0;c<16;++c){ red[w][c]=sum[c]; red[w][16+c]=sq[c]; }
  }
  __syncthreads();
  if(t<32) stat[t]=red[0][t]+red[1][t]+red[2][t]+red[3][t];
  __syncthreads();
  if(t<16){
    float mu  = stat[t]*(1.f/SITES);
    float var = stat[16+t]*(1.f/SITES) - mu*mu;
    float sc  = bng[t] * rsqrtf(var + 1e-5f);
    ssc[t]=sc; ssh[t]=bnb[t] - mu*sc;
  }
  __syncthreads();
  {
    float sc[16], sh[16];
    #pragma unroll
    for(int c=0;c<16;++c){ sc[c]=ssc[c]; sh[c]=ssh[c]; }
    #pragma unroll
    for(int s=0;s<8;++s){
      const int n = w*32 + (s>>2)*16 + quad*4 + (s&3);
      const int node = b*NN + n;
      float r[16];
      #pragma unroll
      for(int c=0;c<16;++c) r[c]=fmaxf(h[s][c]*sc[c]+sh[c], 0.f);
      uint4 A;
      A.x=pk2(r[0],r[1]);  A.y=pk2(r[2],r[3]);  A.z=pk2(r[4],r[5]);  A.w=pk2(r[6],r[7]);
      uint4 Bv;
      Bv.x=pk2(r[8],r[9]); Bv.y=pk2(r[10],r[11]); Bv.z=pk2(r[12],r[13]); Bv.w=pk2(r[14],r[15]);
      u16* o = h1 + (size_t)node*256 + (size_t)col*HM;
      *(uint4*)o     = A;
      *(uint4*)(o+8) = Bv;
    }
  }
}

// --------------------------- CSR build (by dst) ----------------------------
__global__ void k_hist(const int* __restrict__ dst, int* __restrict__ cnt){
  int e = blockIdx.x*256 + threadIdx.x;
  atomicAdd(&cnt[dst[e]], 1);
}

// ---------------------------------------------------------------------------
// K-perm R15: counting sort by degree (64 bins) that ALSO emits perm-ordered
// edge offsets for free (all nodes in bin b have degree exactly b, so the
// j-th node of bin b starts at ebase[b] + j*b). Outputs perm, offP, and
// scatter cursors (cntw in place). Per-wave sub-histograms. (unchanged)
// ---------------------------------------------------------------------------
__global__ __launch_bounds__(1024) void k_perm(int* cntw, int* __restrict__ perm,
                                               int* __restrict__ offP){
  __shared__ int hist[16][64];
  __shared__ int base[64];
  __shared__ int ebase[64];
  __shared__ int wbase[16][64];
  const int t = threadIdx.x, w = t>>6, l = t&63;
  hist[w][l] = 0;                       // 16x64 = 1024 = blockDim
  __syncthreads();

  int mybin[16];
  #pragma unroll
  for (int i=0;i<16;++i){
    int n = i*1024 + t;                 // coalesced over cnt
    int b = min(cntw[n], 63);
    mybin[i] = b;
    atomicAdd(&hist[w][b], 1);          // within-wave contention only
  }
  __syncthreads();

  if (w == 0){                          // lane l = bin l: dual shfl scan
    int s = 0;
    #pragma unroll
    for (int k=0;k<16;++k) s += hist[k][l];
    int se = s * l;                     // edges in bin l
    int v = s, ve = se;
    #pragma unroll
    for (int d=1; d<64; d<<=1){
      int u  = __shfl_up(v,  d, 64);
      int ue = __shfl_up(ve, d, 64);
      if (l >= d){ v += u; ve += ue; }
    }
    base[l]  = v  - s;                  // exclusive node-space
    ebase[l] = ve - se;                 // exclusive edge-space
  }
  __syncthreads();

  if (w == 1){                          // per-wave placement bases for bin l
    int run = base[l];
    #pragma unroll
    for (int k=0;k<16;++k){ wbase[k][l] = run; run += hist[k][l]; }
  }
  __syncthreads();

  #pragma unroll
  for (int i=0;i<16;++i){
    int b    = mybin[i];
    int pos  = atomicAdd(&wbase[w][b], 1);
    int node = i*1024 + t;
    int e0   = ebase[b] + (pos - base[b]) * b;
    perm[pos] = node;
    offP[pos] = e0;
    cntw[node] = e0;                    // scatter cursor (wpos)
  }
  if (t == 0) offP[NSUM] = NE;
}

__global__ void k_scatter(const int* __restrict__ srcI, const int* __restrict__ dstI,
                          int* __restrict__ wpos, int* __restrict__ srcs){
  int e = blockIdx.x*256 + threadIdx.x;
  int p = atomicAdd(&wpos[dstI[e]], 1);
  srcs[p] = srcI[e];
}

// ---------------------------------------------------------------------------
// K4a: GIN-1 aggregate, sorted-position-indexed. (unchanged from R15)
// ---------------------------------------------------------------------------
__global__ __launch_bounds__(256) void k_agg1(
  const u16* __restrict__ h1, const float* __restrict__ eps1p,
  const int* __restrict__ offP, const int* __restrict__ perm,
  const int* __restrict__ srcs, u16* __restrict__ z1)
{
  const int t=threadIdx.x, l=t&63;
  const int p = blockIdx.x*4 + (t>>6);
  const int node = perm[p];
  const float epe = 1.f + eps1p[0];
  float a[4] = {0.f,0.f,0.f,0.f};
  acc4s(a, *(const uint2*)&h1[(size_t)node*256 + l*4], epe);
  int e = offP[p]; const int e1 = offP[p+1];
  for(; e+8<=e1; e+=8){
    int s0=srcs[e],s1=srcs[e+1],s2=srcs[e+2],s3=srcs[e+3];
    int s4=srcs[e+4],s5=srcs[e+5],s6=srcs[e+6],s7=srcs[e+7];
    uint2 r0=*(const uint2*)&h1[(size_t)s0*256 + l*4];
    uint2 r1=*(const uint2*)&h1[(size_t)s1*256 + l*4];
    uint2 r2=*(const uint2*)&h1[(size_t)s2*256 + l*4];
    uint2 r3=*(const uint2*)&h1[(size_t)s3*256 + l*4];
    uint2 r4=*(const uint2*)&h1[(size_t)s4*256 + l*4];
    uint2 r5=*(const uint2*)&h1[(size_t)s5*256 + l*4];
    uint2 r6=*(const uint2*)&h1[(size_t)s6*256 + l*4];
    uint2 r7=*(const uint2*)&h1[(size_t)s7*256 + l*4];
    acc4s(a,r0,1.f); acc4s(a,r1,1.f); acc4s(a,r2,1.f); acc4s(a,r3,1.f);
    acc4s(a,r4,1.f); acc4s(a,r5,1.f); acc4s(a,r6,1.f); acc4s(a,r7,1.f);
  }
  for(; e<e1; ++e){
    uint2 r=*(const uint2*)&h1[(size_t)srcs[e]*256 + l*4];
    acc4s(a,r,1.f);
  }
  uint2 o; o.x=pk2(a[0],a[1]); o.y=pk2(a[2],a[3]);
  *(uint2*)&z1[(size_t)node*256 + l*4] = o;
}

// ---------------------------------------------------------------------------
// K5a: GIN-2 aggregate. (unchanged from R15: batch-4, perm-ordered edges,
// one m-slice per block, stride-balanced sorted chunks)
// ---------------------------------------------------------------------------
__global__ __launch_bounds__(256) void k_agg2(
  const u16* __restrict__ h2T, const float* __restrict__ eps2p,
  const int* __restrict__ offP, const int* __restrict__ srcs,
  const int* __restrict__ perm, u16* __restrict__ z2)
{
  const int t=threadIdx.x, l=t&63, w=t>>6;
  const int m = blockIdx.x & 15, g = blockIdx.x >> 4;   // g in [0,512)
  const int grp = l>>3, q = l&7;
  const int p = (w*512 + g)*8 + grp;                    // sorted position
  const int node = perm[p];
  const float epe = 1.f + eps2p[0];
  const u16* __restrict__ base = h2T + (size_t)m*(NSUM*DP);

  f32x2 A[4];
  {
    uint4 x = *(const uint4*)&base[(size_t)node*DP + q*8];
    f32x2 s2; s2.x=epe; s2.y=epe;
    A[0]=s2*up2(x.x); A[1]=s2*up2(x.y); A[2]=s2*up2(x.z); A[3]=s2*up2(x.w);
  }
  const int e0 = offP[p], e1 = offP[p+1];
  int dmin = e1 - e0, dmax = dmin;
  #pragma unroll
  for(int d=1; d<64; d<<=1){
    dmin = min(dmin, __shfl_xor(dmin, d, 64));
    dmax = max(dmax, __shfl_xor(dmax, d, 64));
  }
  const int dmin4 = dmin & ~3;

  int i = 0;
  // fast path: all 8 nodes in every lane-group have >= dmin edges.
  for(; i < dmin4; i += 4){
    int i0 = srcs[e0+i],   i1 = srcs[e0+i+1];
    int i2 = srcs[e0+i+2], i3 = srcs[e0+i+3];
    uint4 x0 = *(const uint4*)&base[(size_t)i0*DP + q*8];
    uint4 x1 = *(const uint4*)&base[(size_t)i1*DP + q*8];
    uint4 x2 = *(const uint4*)&base[(size_t)i2*DP + q*8];
    uint4 x3 = *(const uint4*)&base[(size_t)i3*DP + q*8];
    A[0]+=up2(x0.x); A[1]+=up2(x0.y); A[2]+=up2(x0.z); A[3]+=up2(x0.w);
    A[0]+=up2(x1.x); A[1]+=up2(x1.y); A[2]+=up2(x1.z); A[3]+=up2(x1.w);
    A[0]+=up2(x2.x); A[1]+=up2(x2.y); A[2]+=up2(x2.z); A[3]+=up2(x2.w);
    A[0]+=up2(x3.x); A[1]+=up2(x3.y); A[2]+=up2(x3.z); A[3]+=up2(x3.w);
  }
  // tail: dmin4..dmax, scale-predicated (masked lanes accumulate x0).
  for(; i < dmax; ++i){
    int pa = e0+i;
    float sa = (pa < e1) ? 1.f : 0.f;
    int ea = min(pa, NE-1);
    int ia = srcs[ea];
    uint4 xa = *(const uint4*)&base[(size_t)ia*DP + q*8];
    f32x2 va; va.x=sa; va.y=sa;
    A[0]+=va*up2(xa.x); A[1]+=va*up2(xa.y); A[2]+=va*up2(xa.z); A[3]+=va*up2(xa.w);
  }

  uint4 o;
  o.x=pk2(A[0].x,A[0].y); o.y=pk2(A[1].x,A[1].y);
  o.z=pk2(A[2].x,A[2].y); o.w=pk2(A[3].x,A[3].y);
  *(uint4*)&z2[(size_t)node*1024 + m*DP + q*8] = o;
}

// ---------------------------------------------------------------------------
// K4b: GIN-1 MLP via MFMA; writes h2T[m][node][d]. (R16: 32 nodes/block)
// ---------------------------------------------------------------------------
__global__ __launch_bounds__(256) void k_mm1(
  const u16* __restrict__ z1, const float* __restrict__ W1a, const float* __restrict__ b1a,
  const float* __restrict__ W1b, const float* __restrict__ b1b, u16* __restrict__ h2T)
{
  __shared__ float tS[4][16*68 + 4];
  const int t=threadIdx.x, l=t&63, w=t>>6;
  const int col=l&15, quad=l>>4;

  bf16x8 fa[4], fb[4][2];
  float bav[4], bbv[4];
  #pragma unroll
  for(int nt=0;nt<4;++nt){
    fa[nt]    = bfragW(W1a, HM, 0,  nt*16, col, quad);   // k>=16 zeroed
    fb[nt][0] = bfragW(W1b, DP, 0,  nt*16, col, quad);
    fb[nt][1] = bfragW(W1b, DP, 32, nt*16, col, quad);
    bav[nt] = b1a[nt*16+col];
    bbv[nt] = b1b[nt*16+col];
  }
  for(int ni=0;ni<8;++ni){
    const int node = blockIdx.x*32 + ni*4 + w;
    bf16x8 a0;
    #pragma unroll
    for(int j=0;j<8;++j) a0[j]=0;
    if (quad < 2) a0 = *(const bf16x8*)&z1[(size_t)node*256 + col*16 + quad*8];
    #pragma unroll
    for(int nt=0;nt<4;++nt){
      f32x4 c = {bav[nt], bav[nt], bav[nt], bav[nt]};
      c = MFMA16(a0, fa[nt], c);
      #pragma unroll
      for(int r=0;r<4;++r)
        tS[w][(quad*4+r)*68 + nt*16 + col] = fmaxf(c[r], 0.f);
    }
    bf16x8 ta0 = afragT(&tS[w][col*68 + quad*8]);
    bf16x8 ta1 = afragT(&tS[w][col*68 + 32 + quad*8]);
    #pragma unroll
    for(int nt=0;nt<4;++nt){
      f32x4 c = {bbv[nt], bbv[nt], bbv[nt], bbv[nt]};
      c = MFMA16(ta0, fb[nt][0], c);
      c = MFMA16(ta1, fb[nt][1], c);
      #pragma unroll
      for(int r=0;r<4;++r)
        h2T[((size_t)(quad*4+r)*NSUM + node)*DP + nt*16 + col] = f2b(fmaxf(c[r], 0.f));
    }
  }
}

// ---------------------------------------------------------------------------
// K5b: GIN-2 MLP via MFMA + ReLU + sum over M -> out f32 [NSUM,64].
// (R16: 32 nodes/block)
// ---------------------------------------------------------------------------
__global__ __launch_bounds__(256) void k_mm2(
  const u16* __restrict__ z2, const float* __restrict__ W2a, const float* __restrict__ b2a,
  const float* __restrict__ W2b, const float* __restrict__ b2b, float* __restrict__ out)
{
  __shared__ float tS[4][16*68 + 4];
  const int t=threadIdx.x, l=t&63, w=t>>6;
  const int col=l&15, quad=l>>4;

  bf16x8 fa[4][2], fb[4][2];
  float bav[4], bbv[4];
  #pragma unroll
  for(int nt=0;nt<4;++nt){
    fa[nt][0] = bfragW(W2a, DP, 0,  nt*16, col, quad);
    fa[nt][1] = bfragW(W2a, DP, 32, nt*16, col, quad);
    fb[nt][0] = bfragW(W2b, DP, 0,  nt*16, col, quad);
    fb[nt][1] = bfragW(W2b, DP, 32, nt*16, col, quad);
    bav[nt] = b2a[nt*16+col];
    bbv[nt] = b2b[nt*16+col];
  }
  for(int ni=0;ni<8;++ni){
    const int node = blockIdx.x*32 + ni*4 + w;
    const u16* zrow = &z2[(size_t)node*1024];
    bf16x8 a0 = *(const bf16x8*)&zrow[col*64 + quad*8];
    bf16x8 a1 = *(const bf16x8*)&zrow[col*64 + quad*8 + 32];
    #pragma unroll
    for(int nt=0;nt<4;++nt){
      f32x4 c = {bav[nt], bav[nt], bav[nt], bav[nt]};
      c = MFMA16(a0, fa[nt][0], c);
      c = MFMA16(a1, fa[nt][1], c);
      #pragma unroll
      for(int r=0;r<4;++r)
        tS[w][(quad*4+r)*68 + nt*16 + col] = fmaxf(c[r], 0.f);
    }
    bf16x8 ta0 = afragT(&tS[w][col*68 + quad*8]);
    bf16x8 ta1 = afragT(&tS[w][col*68 + 32 + quad*8]);
    #pragma unroll
    for(int nt=0;nt<4;++nt){
      f32x4 c = {bbv[nt], bbv[nt], bbv[nt], bbv[nt]};
      c = MFMA16(ta0, fb[nt][0], c);
      c = MFMA16(ta1, fb[nt][1], c);
      float s = fmaxf(c[0],0.f)+fmaxf(c[1],0.f)+fmaxf(c[2],0.f)+fmaxf(c[3],0.f);
      s += __shfl_xor(s, 16, 64);
      s += __shfl_xor(s, 32, 64);
      if (quad == 0)
        out[(size_t)node*64 + nt*16 + col] = s;
    }
  }
}

extern "C" void kernel_launch(void* const* d_in, const int* in_sizes, int n_in,
                              void* d_out, int out_size, void* d_ws, size_t ws_size,
                              hipStream_t stream)
{
  (void)in_sizes; (void)n_in; (void)out_size; (void)ws_size;
  const float* lap  = (const float*)d_in[0];
  const float* W0   = (const float*)d_in[1];
  const float* mlpW = (const float*)d_in[2];
  // d_in[3] = mlp_b: cancels inside BatchNorm (pure mean shift)
  const float* bng  = (const float*)d_in[4];
  const float* bnb  = (const float*)d_in[5];
  const float* eps1 = (const float*)d_in[6];
  const float* W1a  = (const float*)d_in[7];
  const float* b1a  = (const float*)d_in[8];
  const float* W1b  = (const float*)d_in[9];
  const float* b1b  = (const float*)d_in[10];
  const float* eps2 = (const float*)d_in[11];
  const float* W2a  = (const float*)d_in[12];
  const float* b2a  = (const float*)d_in[13];
  const float* W2b  = (const float*)d_in[14];
  const float* b2b  = (const float*)d_in[15];
  const int*   ei   = (const int*)d_in[16];
  const int* srcI = ei;
  const int* dstI = ei + NE;

  char* ws = (char*)d_ws;
  u16* h1   = (u16*)(ws);                    //  8,388,608 B  [16384][16][16]
  u16* z1   = (u16*)(ws + 8388608);          //  8,388,608 B
  u16* h2T  = (u16*)(ws + 16777216);         // 33,554,432 B  [16][16384][64]
  u16* z2   = (u16*)(ws + 50331648);         // 33,554,432 B  [16384][16][64]
  int* cntw = (int*)(ws + 83886080);         //     65,536 B  cnt, then wpos
  int* offP = (int*)(ws + 83951616);         //     65,792 B  sorted edge offs
  int* perm = (int*)(ws + 84017408);         //     65,536 B  degree-sort perm
  int* srcs = (int*)(ws + 84082944);         //  1,048,576 B  perm-ordered edges

  k_poly   <<<BG,      256, 0, stream>>>(lap, W0, mlpW, bng, bnb, h1, cntw);
  k_hist   <<<NE/256,  256, 0, stream>>>(dstI, cntw);
  k_perm   <<<1,      1024, 0, stream>>>(cntw, perm, offP);
  k_scatter<<<NE/256,  256, 0, stream>>>(srcI, dstI, cntw, srcs);
  k_agg1   <<<NSUM/4,  256, 0, stream>>>(h1, eps1, offP, perm, srcs, z1);
  k_mm1    <<<NSUM/32, 256, 0, stream>>>(z1, W1a, b1a, W1b, b1b, h2T);
  k_agg2   <<<16*(NSUM/32), 256, 0, stream>>>(h2T, eps2, offP, srcs, perm, z2);
  k_mm2    <<<NSUM/32, 256, 0, stream>>>(z2, W2a, b2a, W2b, b2b, (float*)d_out);
}